// Round 1
// 465.962 us; speedup vs baseline: 1.4400x; 1.4400x over previous
//
#include <hip/hip_runtime.h>

#define N_NODES 20000
#define E_EDGES 640000
#define R_REL   64
#define B_BASES 16

typedef __attribute__((ext_vector_type(4))) float f32x4;
typedef __attribute__((ext_vector_type(8))) short short8;

__device__ inline float bf2f(unsigned short v) {
    unsigned int u = ((unsigned int)v) << 16;
    return __uint_as_float(u);
}
__device__ inline unsigned short f2bf(float f) {
    unsigned int u = __float_as_uint(f);
    unsigned int r = (u + 0x7FFF + ((u >> 16) & 1)) >> 16;  // RNE
    return (unsigned short)r;
}

__device__ inline void gld_lds16(const void* g, void* l) {
    __builtin_amdgcn_global_load_lds(
        (const __attribute__((address_space(1))) void*)g,
        (__attribute__((address_space(3))) void*)l, 16, 0, 0);
}

// ======================= big-path precompute =======================

// weightT[b][o][i] = weight[b][i][o]  (LDS 32x32 tile transpose)
__global__ void k_wT(const float* w, float* wT)
{
    __shared__ float tile[32][33];
    int b  = blockIdx.x >> 4;
    int ti = (blockIdx.x >> 2) & 3;   // i tile
    int tj = blockIdx.x & 3;          // o tile
    int tx = threadIdx.x & 31, ty = threadIdx.x >> 5;   // 32 x 8
    const float* src = w + b * 16384 + (ti * 32) * 128 + tj * 32;
    for (int s = 0; s < 4; s++)
        tile[ty + s * 8][tx] = src[(ty + s * 8) * 128 + tx];
    __syncthreads();
    float* dstp = wT + b * 16384 + (tj * 32) * 128 + ti * 32;
    for (int s = 0; s < 4; s++)
        dstp[(ty + s * 8) * 128 + tx] = tile[tx][ty + s * 8];
}

// Wt planes: wt_hi/wt_lo[r][o][i] (bf16 hi + residual lo)
__global__ void k_wrel_t(const float* weightT, const float* w_comp,
                         unsigned short* wt_hi, unsigned short* wt_lo)
{
    int idx = blockIdx.x * 256 + threadIdx.x;
    int r  = idx >> 14;
    int oi = idx & 16383;
    float acc = 0.0f;
    for (int b = 0; b < B_BASES; b++)
        acc += w_comp[r * B_BASES + b] * weightT[b * 16384 + oi];
    unsigned short hi = f2bf(acc);
    unsigned short lo = f2bf(acc - bf2f(hi));
    wt_hi[idx] = hi;
    wt_lo[idx] = lo;
}

// x planes: x_hi/x_lo (bf16 hi + residual lo), 2 elems/thread
__global__ void k_xsplit(const float* x, unsigned short* xg_hi, unsigned short* xg_lo)
{
    int i2 = blockIdx.x * 256 + threadIdx.x;   // over N*128/2
    float2 v = ((const float2*)x)[i2];
    ushort2 h, l;
    h.x = f2bf(v.x); l.x = f2bf(v.x - bf2f(h.x));
    h.y = f2bf(v.y); l.y = f2bf(v.y - bf2f(h.y));
    ((ushort2*)xg_hi)[i2] = h;
    ((ushort2*)xg_lo)[i2] = l;
}

// zero counts (64) + counts2 (20000)
__global__ void k_zero_small(int* counts, int* counts2)
{
    int idx = blockIdx.x * 256 + threadIdx.x;
    if (idx < R_REL) counts[idx] = 0;
    if (idx < N_NODES) counts2[idx] = 0;
}

// one pass over E: etype hist (LDS) + dst hist (global atomics)
__global__ void k_hist_all(const int* etypes, const int* dst, int* counts, int* counts2)
{
    __shared__ int h[R_REL];
    int t = threadIdx.x;
    if (t < R_REL) h[t] = 0;
    __syncthreads();
    int e = blockIdx.x * 256 + t;
    atomicAdd(&h[etypes[e]], 1);
    atomicAdd(&counts2[dst[e]], 1);
    __syncthreads();
    if (t < R_REL && h[t] != 0) atomicAdd(&counts[t], h[t]);
}

// single block: wave-scan of 64 etype counts + 256-thread scan of 20000 dst counts
__global__ void k_scan_all(const int* counts, const int* counts2,
                           int* offsets, int* cursor, int* co,
                           int* off2, int* cursor2)
{
    int t = threadIdx.x;
    if (t < 64) {
        int c  = counts[t];
        int ch = (c + 63) >> 6;
        int s1 = c, s2 = ch;
        for (int d = 1; d < 64; d <<= 1) {
            int a1 = __shfl_up(s1, d);
            int a2 = __shfl_up(s2, d);
            if (t >= d) { s1 += a1; s2 += a2; }
        }
        offsets[t] = s1 - c; cursor[t] = s1 - c; co[t] = s2 - ch;
        if (t == 63) { offsets[64] = s1; co[64] = s2; }
    }
    __shared__ int part[256];
    int lo_i = t * 79, hi_i = lo_i + 79;
    if (hi_i > N_NODES) hi_i = N_NODES;
    if (lo_i > N_NODES) lo_i = N_NODES;
    int s = 0;
    for (int i = lo_i; i < hi_i; i++) s += counts2[i];
    part[t] = s;
    __syncthreads();
    for (int d = 1; d < 256; d <<= 1) {
        int v = (t >= d) ? part[t - d] : 0;
        __syncthreads();
        part[t] += v;
        __syncthreads();
    }
    int run = part[t] - s;
    for (int i = lo_i; i < hi_i; i++) {
        off2[i] = run; cursor2[i] = run;
        run += counts2[i];
    }
    if (t == 255) off2[N_NODES] = run;
}

// bucket scatter by etype + dst-sorted slot assignment (order-independent)
__global__ void k_scatter2(const int* etypes, const int* dst,
                           int* cursor, int* cursor2, int* perm, int* pos2)
{
    __shared__ int h[R_REL];
    __shared__ int base[R_REL];
    int t = threadIdx.x;
    if (t < R_REL) h[t] = 0;
    __syncthreads();
    int e = blockIdx.x * 256 + t;
    int et = etypes[e];
    int rank = atomicAdd(&h[et], 1);
    __syncthreads();
    if (t < R_REL && h[t] != 0) base[t] = atomicAdd(&cursor[t], h[t]);
    __syncthreads();
    int p = base[et] + rank;
    perm[p] = e;
    int slot = atomicAdd(&cursor2[dst[e]], 1);
    pos2[p] = slot;
}

// ---- Phase A: per 64-edge chunk, hi/lo split-bf16 MFMA GEMM ----
// msg[slot] = (x[src] @ Wt[r]^T) * norm, bf16, stored at dst-sorted slot
__global__ __launch_bounds__(256, 3) void k_edge_mfma(
    const unsigned short* xg_hi, const unsigned short* xg_lo,
    const unsigned short* wt_hi, const unsigned short* wt_lo,
    const float* norm, const int* src, const int* perm, const int* pos2,
    const int* offsets, const int* co, unsigned short* msg)
{
    // LDS map (16B slots): x_hi [0,512), x_lo [512,1024), w_hi [1024,2048), w_lo [2048,3072)
    __shared__ __align__(16) char smem[49152];
    __shared__ int coS[R_REL + 1];
    __shared__ int srcS[64];
    __shared__ float normS[64];

    int t = threadIdx.x, bid = blockIdx.x;
    if (t <= R_REL) coS[t] = co[t];
    __syncthreads();
    if (bid >= coS[R_REL]) return;
    int r = 0;
    while (bid >= coS[r + 1]) r++;
    int e0 = offsets[r] + (bid - coS[r]) * 64;
    int cnt = offsets[r + 1] - e0;
    if (cnt > 64) cnt = 64;
    if (t < 64) {
        if (t < cnt) {
            int eid = perm[e0 + t];
            srcS[t] = src[eid]; normS[t] = norm[eid];
        } else { srcS[t] = 0; normS[t] = 0.0f; }
    }

    int l  = t & 63, w = t >> 6;
    int lg = l >> 4, lr = l & 15;
    int wr = w >> 1, wc = w & 1;        // wave -> (row-half, col-half) of 64x128

    f32x4 acc[2][4];
    #pragma unroll
    for (int a = 0; a < 2; a++)
        #pragma unroll
        for (int n = 0; n < 4; n++)
            acc[a][n] = {0.0f, 0.0f, 0.0f, 0.0f};

    const short8* sm8 = (const short8*)smem;
    size_t rbase = (size_t)r * 16384;

    __syncthreads();   // srcS ready

    for (int h = 0; h < 2; h++) {       // K halves of 64
        // ---- stage 48KB (x hi/lo + W hi/lo) via global_load_lds, pre-swizzled source ----
        #pragma unroll
        for (int it = 0; it < 12; it++) {
            int s = it * 256 + t;
            const unsigned short* g;
            if (s < 512) {
                int e = s >> 3, j = (s & 7) ^ (e & 7);
                g = xg_hi + (size_t)srcS[e] * 128 + h * 64 + j * 8;
            } else if (s < 1024) {
                int ss = s - 512; int e = ss >> 3, j = (ss & 7) ^ (e & 7);
                g = xg_lo + (size_t)srcS[e] * 128 + h * 64 + j * 8;
            } else if (s < 2048) {
                int ss = s - 1024; int o = ss >> 3, j = (ss & 7) ^ (o & 7);
                g = wt_hi + rbase + o * 128 + h * 64 + j * 8;
            } else {
                int ss = s - 2048; int o = ss >> 3, j = (ss & 7) ^ (o & 7);
                g = wt_lo + rbase + o * 128 + h * 64 + j * 8;
            }
            gld_lds16(g, smem + s * 16);
        }
        __syncthreads();
        // ---- compute: 2 k-steps x (2 row-tiles x 4 col-tiles) x 3 hi/lo combos ----
        #pragma unroll
        for (int kk = 0; kk < 2; kk++) {
            short8 ah[2], al[2];
            #pragma unroll
            for (int a = 0; a < 2; a++) {
                int row = wr * 32 + a * 16 + lr;
                int ch  = (kk * 4 + lg) ^ (row & 7);
                ah[a] = sm8[row * 8 + ch];
                al[a] = sm8[512 + row * 8 + ch];
            }
            #pragma unroll
            for (int n = 0; n < 4; n++) {
                int o  = wc * 64 + n * 16 + lr;
                int ch = (kk * 4 + lg) ^ (o & 7);
                short8 bh = sm8[1024 + o * 8 + ch];
                short8 bl = sm8[2048 + o * 8 + ch];
                #pragma unroll
                for (int a = 0; a < 2; a++) {
                    acc[a][n] = __builtin_amdgcn_mfma_f32_16x16x32_bf16(ah[a], bh, acc[a][n], 0, 0, 0);
                    acc[a][n] = __builtin_amdgcn_mfma_f32_16x16x32_bf16(ah[a], bl, acc[a][n], 0, 0, 0);
                    acc[a][n] = __builtin_amdgcn_mfma_f32_16x16x32_bf16(al[a], bh, acc[a][n], 0, 0, 0);
                }
            }
        }
        __syncthreads();   // protect LDS before next-half restage / epilogue reuse
    }

    // ---- epilogue: acc -> LDS (pad 129 vs bank aliasing) -> norm*bf16 packed stores ----
    float* accS = (float*)smem;        // [64][129]
    #pragma unroll
    for (int a = 0; a < 2; a++) {
        #pragma unroll
        for (int n = 0; n < 4; n++) {
            int col = wc * 64 + n * 16 + lr;
            #pragma unroll
            for (int jj = 0; jj < 4; jj++) {
                int row = wr * 32 + a * 16 + lg * 4 + jj;   // C/D: col=lane&15, row=(lane>>4)*4+reg
                accS[row * 129 + col] = acc[a][n][jj];
            }
        }
    }
    __syncthreads();
    int e = t >> 2, cq = (t & 3) * 8;
    if (e < cnt) {
        float nrm = normS[e];
        int slot = pos2[e0 + e];
        unsigned short* mrow = msg + (size_t)slot * 128;
        const float* p = accS + e * 129;
        #pragma unroll
        for (int sgt = 0; sgt < 4; sgt++) {
            int cb = cq + sgt * 32;
            uint4 ov;
            ov.x = (unsigned int)f2bf(p[cb + 0] * nrm) | ((unsigned int)f2bf(p[cb + 1] * nrm) << 16);
            ov.y = (unsigned int)f2bf(p[cb + 2] * nrm) | ((unsigned int)f2bf(p[cb + 3] * nrm) << 16);
            ov.z = (unsigned int)f2bf(p[cb + 4] * nrm) | ((unsigned int)f2bf(p[cb + 5] * nrm) << 16);
            ov.w = (unsigned int)f2bf(p[cb + 6] * nrm) | ((unsigned int)f2bf(p[cb + 7] * nrm) << 16);
            *(uint4*)(mrow + cb) = ov;
        }
    }
}

// ---- self-loop GEMM: out[n][o] = x[n]@loop_w[:,o] + bias[o]  (f32, no relu yet) ----
__global__ void k_selfgemm(const float* x, const float* loop_w, const float* bias,
                           float* out)
{
    __shared__ float4 WfS[2048];     // [i=64][o/4=32]
    __shared__ float4 xsS[1024];     // [n=64][i/4=16]
    int t = threadIdx.x, bid = blockIdx.x;
    int n0 = bid * 64;
    const float* xsf = (const float*)xsS;
    int q  = t & 31;
    int eb = t >> 5;
    float4 acc[8];
    for (int k = 0; k < 8; k++) { acc[k].x = 0.f; acc[k].y = 0.f; acc[k].z = 0.f; acc[k].w = 0.f; }
    for (int h = 0; h < 2; h++) {
        __syncthreads();
        const float4* Wsrc = (const float4*)(loop_w + h * 8192);
        for (int p = 0; p < 8; p++) WfS[p * 256 + t] = Wsrc[p * 256 + t];
        for (int p = 0; p < 4; p++) {
            int idx = p * 256 + t;
            int e = idx >> 4, c = idx & 15;
            int n = n0 + e; if (n >= N_NODES) n = N_NODES - 1;
            xsS[idx] = ((const float4*)(x + n * 128 + h * 64))[c];
        }
        __syncthreads();
        for (int i = 0; i < 64; i++) {
            float4 wv = WfS[i * 32 + q];
            for (int k = 0; k < 8; k++) {
                float xv = xsf[(eb + 8 * k) * 64 + i];
                acc[k].x += xv * wv.x;
                acc[k].y += xv * wv.y;
                acc[k].z += xv * wv.z;
                acc[k].w += xv * wv.w;
            }
        }
    }
    float4 b4 = *((const float4*)(bias + q * 4));
    for (int k = 0; k < 8; k++) {
        int n = n0 + eb + 8 * k;
        if (n < N_NODES) {
            float4 v;
            v.x = acc[k].x + b4.x;
            v.y = acc[k].y + b4.y;
            v.z = acc[k].z + b4.z;
            v.w = acc[k].w + b4.w;
            *((float4*)(out + (size_t)n * 128 + q * 4)) = v;
        }
    }
}

// ---- msg reduction: 8 rows in parallel, uint2 loads, LDS tree ----
__global__ void k_msgsum(const unsigned short* msg, const int* off2, float* out)
{
    __shared__ float4 red[256];
    int n = blockIdx.x, t = threadIdx.x;
    int m0 = off2[n], m1 = off2[n + 1];
    int rp = t >> 5, c = t & 31;
    float4 a; a.x = 0.f; a.y = 0.f; a.z = 0.f; a.w = 0.f;
    for (int j = m0 + rp; j < m1; j += 8) {
        uint2 v = *(const uint2*)(msg + (size_t)j * 128 + c * 4);
        a.x += __uint_as_float(v.x << 16);
        a.y += __uint_as_float(v.x & 0xffff0000u);
        a.z += __uint_as_float(v.y << 16);
        a.w += __uint_as_float(v.y & 0xffff0000u);
    }
    red[t] = a;
    __syncthreads();
    if (t < 128) {
        float4 b = red[t + 128];
        red[t].x += b.x; red[t].y += b.y; red[t].z += b.z; red[t].w += b.w;
    }
    __syncthreads();
    if (t < 64) {
        float4 b = red[t + 64];
        red[t].x += b.x; red[t].y += b.y; red[t].z += b.z; red[t].w += b.w;
    }
    __syncthreads();
    if (t < 32) {
        float4 v = red[t], b = red[t + 32];
        v.x += b.x; v.y += b.y; v.z += b.z; v.w += b.w;
        float4 o = *(const float4*)(out + (size_t)n * 128 + t * 4);
        v.x += o.x; v.y += o.y; v.z += o.z; v.w += o.w;
        if (v.x < 0.f) v.x = 0.f;
        if (v.y < 0.f) v.y = 0.f;
        if (v.z < 0.f) v.z = 0.f;
        if (v.w < 0.f) v.w = 0.f;
        *(float4*)(out + (size_t)n * 128 + t * 4) = v;
    }
}

// ======================= fallback path (small ws) =======================

__global__ void k_wrel(const float* weight, const float* w_comp, float* W_rel)
{
    int idx = blockIdx.x * 256 + threadIdx.x;
    int r  = idx >> 14;
    int io = idx & 16383;
    float acc = 0.0f;
    for (int b = 0; b < B_BASES; b++)
        acc += w_comp[r * B_BASES + b] * weight[b * 16384 + io];
    W_rel[idx] = acc;
}

__global__ void k_zero(float* agg, int* counts, int* counts2)
{
    int idx = blockIdx.x * 256 + threadIdx.x;
    if (idx < N_NODES * 128) agg[idx] = 0.0f;
    if (idx < R_REL) counts[idx] = 0;
    if (idx < N_NODES) counts2[idx] = 0;
}

__global__ void k_hist(const int* etypes, int* counts)
{
    __shared__ int h[R_REL];
    int t = threadIdx.x;
    if (t < R_REL) h[t] = 0;
    __syncthreads();
    int e = blockIdx.x * 256 + t;
    atomicAdd(&h[etypes[e]], 1);
    __syncthreads();
    if (t < R_REL && h[t] != 0) atomicAdd(&counts[t], h[t]);
}

__global__ void k_scan(const int* counts, int* offsets, int* cursor, int* co)
{
    if (threadIdx.x == 0) {
        int run = 0, c = 0;
        for (int r = 0; r < R_REL; r++) {
            offsets[r] = run; cursor[r] = run; co[r] = c;
            run += counts[r];
            c   += (counts[r] + 63) >> 6;
        }
        offsets[R_REL] = run; co[R_REL] = c;
    }
}

__global__ void k_scatter(const int* etypes, int* cursor, int* perm)
{
    __shared__ int h[R_REL];
    __shared__ int base[R_REL];
    int t = threadIdx.x;
    if (t < R_REL) h[t] = 0;
    __syncthreads();
    int e = blockIdx.x * 256 + t;
    int et = etypes[e];
    int rank = atomicAdd(&h[et], 1);
    __syncthreads();
    if (t < R_REL && h[t] != 0) base[t] = atomicAdd(&cursor[t], h[t]);
    __syncthreads();
    perm[base[et] + rank] = e;
}

__global__ void k_edge_atomic(const float* x, const float* W_rel, const float* norm,
                              const int* src, const int* dst, const int* perm,
                              const int* offsets, const int* co, float* agg)
{
    __shared__ float4 WfS[2048];
    __shared__ float4 xsS[1024];
    __shared__ int coS[R_REL + 1];
    __shared__ int srcS[64], dstS[64];
    __shared__ float normS[64];
    int t = threadIdx.x, bid = blockIdx.x;
    if (t <= R_REL) coS[t] = co[t];
    __syncthreads();
    if (bid >= coS[R_REL]) return;
    int r = 0;
    while (bid >= coS[r + 1]) r++;
    int e0 = offsets[r] + (bid - coS[r]) * 64;
    int cnt = offsets[r + 1] - e0;
    if (cnt > 64) cnt = 64;
    if (t < 64) {
        if (t < cnt) {
            int eid = perm[e0 + t];
            srcS[t] = src[eid]; dstS[t] = dst[eid]; normS[t] = norm[eid];
        } else { srcS[t] = 0; dstS[t] = 0; normS[t] = 0.0f; }
    }
    const float* xsf = (const float*)xsS;
    int q  = t & 31;
    int eb = t >> 5;
    float4 acc[8];
    for (int k = 0; k < 8; k++) { acc[k].x = 0.f; acc[k].y = 0.f; acc[k].z = 0.f; acc[k].w = 0.f; }
    for (int h = 0; h < 2; h++) {
        __syncthreads();
        const float4* Wsrc = (const float4*)(W_rel + r * 16384 + h * 8192);
        for (int p = 0; p < 8; p++) WfS[p * 256 + t] = Wsrc[p * 256 + t];
        for (int p = 0; p < 4; p++) {
            int idx = p * 256 + t;
            int e = idx >> 4, c = idx & 15;
            xsS[idx] = ((const float4*)(x + srcS[e] * 128 + h * 64))[c];
        }
        __syncthreads();
        for (int i = 0; i < 64; i++) {
            float4 wv = WfS[i * 32 + q];
            for (int k = 0; k < 8; k++) {
                float xv = xsf[(eb + 8 * k) * 64 + i];
                acc[k].x += xv * wv.x;
                acc[k].y += xv * wv.y;
                acc[k].z += xv * wv.z;
                acc[k].w += xv * wv.w;
            }
        }
    }
    for (int k = 0; k < 8; k++) {
        int e = eb + 8 * k;
        if (e < cnt) {
            float nrm = normS[e];
            float* row = agg + dstS[e] * 128 + q * 4;
            atomicAdd(row + 0, acc[k].x * nrm);
            atomicAdd(row + 1, acc[k].y * nrm);
            atomicAdd(row + 2, acc[k].z * nrm);
            atomicAdd(row + 3, acc[k].w * nrm);
        }
    }
}

__global__ void k_out(const float* x, const float* loop_w, const float* agg,
                      const float* bias, float* out)
{
    __shared__ float xrow[128];
    int n = blockIdx.x;
    int o = threadIdx.x;
    xrow[o] = x[n * 128 + o];
    __syncthreads();
    float acc = 0.0f;
    for (int i = 0; i < 128; i++)
        acc += xrow[i] * loop_w[i * 128 + o];
    float val = acc + agg[n * 128 + o] + bias[o];
    if (val < 0.0f) val = 0.0f;
    out[n * 128 + o] = val;
}

extern "C" void kernel_launch(void* const* d_in, const int* in_sizes, int n_in,
                              void* d_out, int out_size, void* d_ws, size_t ws_size,
                              hipStream_t stream)
{
    const float* x      = (const float*)d_in[0];
    const float* weight = (const float*)d_in[1];
    const float* w_comp = (const float*)d_in[2];
    const float* h_bias = (const float*)d_in[3];
    const float* loop_w = (const float*)d_in[4];
    const float* norm   = (const float*)d_in[5];
    const int* src    = (const int*)d_in[6];
    const int* dst    = (const int*)d_in[7];
    const int* etypes = (const int*)d_in[8];
    float* out = (float*)d_out;

    char* ws = (char*)d_ws;
    size_t off = 0;
    float* W_rel = (float*)(ws + off); off += (size_t)R_REL * 16384 * 4;      // big: Wt planes
    float* agg   = (float*)(ws + off); off += (size_t)N_NODES * 128 * 4;      // big: x planes
    int* perm    = (int*)(ws + off);   off += (size_t)E_EDGES * 4;
    int* counts  = (int*)(ws + off);   off += 64 * 4;
    int* offsets = (int*)(ws + off);   off += 68 * 4;
    int* cursor  = (int*)(ws + off);   off += 64 * 4;
    int* co      = (int*)(ws + off);   off += 68 * 4;
    int* counts2 = (int*)(ws + off);   off += (size_t)N_NODES * 4;
    int* off2    = (int*)(ws + off);   off += (size_t)(N_NODES + 4) * 4;      // padded to keep 16B align
    int* cursor2 = (int*)(ws + off);   off += (size_t)N_NODES * 4;
    int* pos2    = (int*)(ws + off);   off += (size_t)E_EDGES * 4;
    unsigned short* msg = (unsigned short*)(ws + off);
    size_t need_big = off + (size_t)E_EDGES * 128 * 2;
    int big = (ws_size >= need_big) ? 1 : 0;

    if (big) {
        // overlays (big path only): Wt planes on W_rel, x planes on agg, weightT on msg head
        unsigned short* wt_hi = (unsigned short*)W_rel;
        unsigned short* wt_lo = wt_hi + (size_t)R_REL * 16384;
        unsigned short* xg_hi = (unsigned short*)agg;
        unsigned short* xg_lo = xg_hi + (size_t)N_NODES * 128;
        float* weightT = (float*)msg;   // consumed by k_wrel_t before msg is written

        k_zero_small<<<(N_NODES + 255) / 256, 256, 0, stream>>>(counts, counts2);
        k_wT<<<256, 256, 0, stream>>>(weight, weightT);
        k_wrel_t<<<(R_REL * 16384) / 256, 256, 0, stream>>>(weightT, w_comp, wt_hi, wt_lo);
        k_xsplit<<<(N_NODES * 128 / 2) / 256, 256, 0, stream>>>(x, xg_hi, xg_lo);
        k_hist_all<<<E_EDGES / 256, 256, 0, stream>>>(etypes, dst, counts, counts2);
        k_scan_all<<<1, 256, 0, stream>>>(counts, counts2, offsets, cursor, co, off2, cursor2);
        k_scatter2<<<E_EDGES / 256, 256, 0, stream>>>(etypes, dst, cursor, cursor2, perm, pos2);
        k_edge_mfma<<<E_EDGES / 64 + R_REL, 256, 0, stream>>>(
            xg_hi, xg_lo, wt_hi, wt_lo, norm, src, perm, pos2, offsets, co, msg);
        k_selfgemm<<<(N_NODES + 63) / 64, 256, 0, stream>>>(x, loop_w, h_bias, out);
        k_msgsum<<<N_NODES, 256, 0, stream>>>(msg, off2, out);
    } else {
        k_wrel<<<(R_REL * 16384) / 256, 256, 0, stream>>>(weight, w_comp, W_rel);
        k_zero<<<(N_NODES * 128) / 256, 256, 0, stream>>>(agg, counts, counts2);
        k_hist<<<E_EDGES / 256, 256, 0, stream>>>(etypes, counts);
        k_scan<<<1, 64, 0, stream>>>(counts, offsets, cursor, co);
        k_scatter<<<E_EDGES / 256, 256, 0, stream>>>(etypes, cursor, perm);
        k_edge_atomic<<<E_EDGES / 64 + R_REL, 256, 0, stream>>>(
            x, W_rel, norm, src, dst, perm, offsets, co, agg);
        k_out<<<N_NODES, 128, 0, stream>>>(x, loop_w, agg, h_bias, out);
    }
}

// Round 2
// 409.809 us; speedup vs baseline: 1.6374x; 1.1370x over previous
//
#include <hip/hip_runtime.h>

#define N_NODES 20000
#define E_EDGES 640000
#define R_REL   64
#define B_BASES 16

typedef __attribute__((ext_vector_type(4))) float f32x4;
typedef __attribute__((ext_vector_type(8))) _Float16 half8;

__device__ inline float h2f(unsigned short v) {
    _Float16 h; __builtin_memcpy(&h, &v, 2); return (float)h;
}
__device__ inline unsigned short f2h(float f) {
    _Float16 h = (_Float16)f; unsigned short v; __builtin_memcpy(&v, &h, 2); return v;
}

__device__ inline void gld_lds16(const void* g, void* l) {
    __builtin_amdgcn_global_load_lds(
        (const __attribute__((address_space(1))) void*)g,
        (__attribute__((address_space(3))) void*)l, 16, 0, 0);
}

// ======================= big-path precompute =======================

// wt_h[r][o][i] = f16( sum_b w_comp[r,b] * weight[b][i][o] )  (fused compose+transpose)
__global__ void k_wrelh(const float* weight, const float* w_comp, unsigned short* wt_h)
{
    __shared__ float tile[32][33];
    __shared__ float wcS[B_BASES];
    int r  = blockIdx.x >> 4;
    int ti = (blockIdx.x >> 2) & 3;   // i tile
    int tj = blockIdx.x & 3;          // o tile
    int tx = threadIdx.x & 31, ty = threadIdx.x >> 5;   // 32 x 8
    if (threadIdx.x < B_BASES) wcS[threadIdx.x] = w_comp[r * B_BASES + threadIdx.x];
    __syncthreads();
    float acc[4] = {0.f, 0.f, 0.f, 0.f};
    const float* wp = weight + (ti * 32) * 128 + tj * 32;
    for (int b = 0; b < B_BASES; b++) {
        float c = wcS[b];
        #pragma unroll
        for (int s = 0; s < 4; s++)
            acc[s] += c * wp[b * 16384 + (ty + s * 8) * 128 + tx];
    }
    #pragma unroll
    for (int s = 0; s < 4; s++) tile[ty + s * 8][tx] = acc[s];   // [i_local][o_local]
    __syncthreads();
    unsigned short* dstp = wt_h + r * 16384 + (tj * 32) * 128 + ti * 32;
    #pragma unroll
    for (int s = 0; s < 4; s++)
        dstp[(ty + s * 8) * 128 + tx] = f2h(tile[tx][ty + s * 8]);
}

// x -> f16
__global__ void k_xhalf(const float* x, unsigned short* xh)
{
    int i4 = blockIdx.x * 256 + threadIdx.x;   // over N*128/4
    float4 v = ((const float4*)x)[i4];
    ushort4 o;
    o.x = f2h(v.x); o.y = f2h(v.y); o.z = f2h(v.z); o.w = f2h(v.w);
    ((ushort4*)xh)[i4] = o;
}

// zero counts (64) + counts2 (20000)
__global__ void k_zero_small(int* counts, int* counts2)
{
    int idx = blockIdx.x * 256 + threadIdx.x;
    if (idx < R_REL) counts[idx] = 0;
    if (idx < N_NODES) counts2[idx] = 0;
}

// one pass over E: etype hist (LDS) + dst hist (global atomics)
__global__ void k_hist_all(const int* etypes, const int* dst, int* counts, int* counts2)
{
    __shared__ int h[R_REL];
    int t = threadIdx.x;
    if (t < R_REL) h[t] = 0;
    __syncthreads();
    int e = blockIdx.x * 256 + t;
    atomicAdd(&h[etypes[e]], 1);
    atomicAdd(&counts2[dst[e]], 1);
    __syncthreads();
    if (t < R_REL && h[t] != 0) atomicAdd(&counts[t], h[t]);
}

// single block, 1024 threads: wave-scan of 64 etype counts + scan of 20000 dst counts
__global__ void k_scan_all(const int* counts, const int* counts2,
                           int* offsets, int* cursor, int* co,
                           int* off2, int* cursor2)
{
    int t = threadIdx.x;
    if (t < 64) {
        int c  = counts[t];
        int ch = (c + 63) >> 6;
        int s1 = c, s2 = ch;
        for (int d = 1; d < 64; d <<= 1) {
            int a1 = __shfl_up(s1, d);
            int a2 = __shfl_up(s2, d);
            if (t >= d) { s1 += a1; s2 += a2; }
        }
        offsets[t] = s1 - c; cursor[t] = s1 - c; co[t] = s2 - ch;
        if (t == 63) { offsets[64] = s1; co[64] = s2; }
    }
    __shared__ int part[1024];
    int lo_i = t * 20, hi_i = lo_i + 20;
    if (hi_i > N_NODES) hi_i = N_NODES;
    if (lo_i > N_NODES) lo_i = N_NODES;
    int s = 0;
    for (int i = lo_i; i < hi_i; i++) s += counts2[i];
    part[t] = s;
    __syncthreads();
    for (int d = 1; d < 1024; d <<= 1) {
        int v = (t >= d) ? part[t - d] : 0;
        __syncthreads();
        part[t] += v;
        __syncthreads();
    }
    int run = part[t] - s;                  // exclusive prefix
    for (int i = lo_i; i < hi_i; i++) {
        off2[i] = run; cursor2[i] = run;
        run += counts2[i];
    }
    if (t == 1023) off2[N_NODES] = run;
}

// bucket scatter by etype + dst-sorted slot assignment (order-independent)
__global__ void k_scatter2(const int* etypes, const int* dst,
                           int* cursor, int* cursor2, int* perm, int* pos2)
{
    __shared__ int h[R_REL];
    __shared__ int base[R_REL];
    int t = threadIdx.x;
    if (t < R_REL) h[t] = 0;
    __syncthreads();
    int e = blockIdx.x * 256 + t;
    int et = etypes[e];
    int rank = atomicAdd(&h[et], 1);
    __syncthreads();
    if (t < R_REL && h[t] != 0) base[t] = atomicAdd(&cursor[t], h[t]);
    __syncthreads();
    int p = base[et] + rank;
    perm[p] = e;
    int slot = atomicAdd(&cursor2[dst[e]], 1);
    pos2[p] = slot;
}

// ---- Phase A: per 64-edge chunk, single-plane f16 MFMA GEMM, full-K stage ----
// msg[slot] = f16( (x[src] @ Wt[r]^T) * norm ), stored at dst-sorted slot
__global__ __launch_bounds__(256, 3) void k_edge_mfma(
    const unsigned short* xh, const unsigned short* wt_h,
    const float* norm, const int* src, const int* perm, const int* pos2,
    const int* offsets, const int* co, unsigned short* msg)
{
    // LDS (16B slots): x [64 rows][16 ch] slots 0..1023 ; W [128 o][16 ch] slots 1024..3071
    __shared__ __align__(16) char smem[49152];
    __shared__ int coS[R_REL + 1];
    __shared__ int srcS[64];
    __shared__ float normS[64];

    int t = threadIdx.x, bid = blockIdx.x;
    if (t <= R_REL) coS[t] = co[t];
    __syncthreads();
    if (bid >= coS[R_REL]) return;
    int r = 0;
    while (bid >= coS[r + 1]) r++;
    int e0 = offsets[r] + (bid - coS[r]) * 64;
    int cnt = offsets[r + 1] - e0;
    if (cnt > 64) cnt = 64;
    if (t < 64) {
        if (t < cnt) {
            int eid = perm[e0 + t];
            srcS[t] = src[eid]; normS[t] = norm[eid];
        } else { srcS[t] = 0; normS[t] = 0.0f; }
    }
    __syncthreads();   // srcS ready

    // stage x (16KB) + W (32KB) via global_load_lds, pre-swizzled source, linear dest
    {
        const size_t rbase = (size_t)r * 16384;
        #pragma unroll
        for (int it = 0; it < 4; it++) {
            int s = it * 256 + t;
            int e = s >> 4, ch = s & 15;
            int j = ch ^ (e & 15);
            gld_lds16(xh + (size_t)srcS[e] * 128 + j * 8, smem + s * 16);
        }
        #pragma unroll
        for (int it = 0; it < 8; it++) {
            int ss = it * 256 + t;
            int o = ss >> 4, ch = ss & 15;
            int j = ch ^ (o & 15);
            gld_lds16(wt_h + rbase + o * 128 + j * 8, smem + 16384 + ss * 16);
        }
    }
    __syncthreads();

    int l  = t & 63, w = t >> 6;
    int lg = l >> 4, lr = l & 15;
    int wr = w >> 1, wc = w & 1;        // wave -> (row-half, col-half) of 64x128

    f32x4 acc[2][4];
    #pragma unroll
    for (int a = 0; a < 2; a++)
        #pragma unroll
        for (int n = 0; n < 4; n++)
            acc[a][n] = {0.0f, 0.0f, 0.0f, 0.0f};

    const half8* smh = (const half8*)smem;
    #pragma unroll
    for (int kk = 0; kk < 4; kk++) {
        half8 av[2];
        #pragma unroll
        for (int a = 0; a < 2; a++) {
            int row = wr * 32 + a * 16 + lr;
            int ch  = (kk * 4 + lg) ^ (row & 15);
            av[a] = smh[row * 16 + ch];
        }
        #pragma unroll
        for (int n = 0; n < 4; n++) {
            int o  = wc * 64 + n * 16 + lr;
            int ch = (kk * 4 + lg) ^ (o & 15);
            half8 bv = smh[1024 + o * 16 + ch];
            #pragma unroll
            for (int a = 0; a < 2; a++)
                acc[a][n] = __builtin_amdgcn_mfma_f32_16x16x32_f16(av[a], bv, acc[a][n], 0, 0, 0);
        }
    }
    __syncthreads();   // all waves done reading LDS before epilogue overwrite

    // ---- epilogue: acc -> LDS (stride 129) -> norm * f16 packed stores ----
    float* accS = (float*)smem;        // [64][129]
    #pragma unroll
    for (int a = 0; a < 2; a++) {
        #pragma unroll
        for (int n = 0; n < 4; n++) {
            int col = wc * 64 + n * 16 + lr;
            #pragma unroll
            for (int jj = 0; jj < 4; jj++) {
                int row = wr * 32 + a * 16 + lg * 4 + jj;   // C/D: col=lane&15, row=(lane>>4)*4+reg
                accS[row * 129 + col] = acc[a][n][jj];
            }
        }
    }
    __syncthreads();
    int e = t >> 2, cq = (t & 3) * 8;
    if (e < cnt) {
        float nrm = normS[e];
        int slot = pos2[e0 + e];
        unsigned short* mrow = msg + (size_t)slot * 128;
        const float* p = accS + e * 129;
        #pragma unroll
        for (int sgt = 0; sgt < 4; sgt++) {
            int cb = cq + sgt * 32;
            uint4 ov;
            ov.x = (unsigned int)f2h(p[cb + 0] * nrm) | ((unsigned int)f2h(p[cb + 1] * nrm) << 16);
            ov.y = (unsigned int)f2h(p[cb + 2] * nrm) | ((unsigned int)f2h(p[cb + 3] * nrm) << 16);
            ov.z = (unsigned int)f2h(p[cb + 4] * nrm) | ((unsigned int)f2h(p[cb + 5] * nrm) << 16);
            ov.w = (unsigned int)f2h(p[cb + 6] * nrm) | ((unsigned int)f2h(p[cb + 7] * nrm) << 16);
            *(uint4*)(mrow + cb) = ov;
        }
    }
}

// ---- self-loop GEMM: out[n][o] = x[n]@loop_w[:,o] + bias[o]  (f32, no relu yet) ----
__global__ void k_selfgemm(const float* x, const float* loop_w, const float* bias,
                           float* out)
{
    __shared__ float4 WfS[2048];     // [i=64][o/4=32]
    __shared__ float4 xsS[1024];     // [n=64][i/4=16]
    int t = threadIdx.x, bid = blockIdx.x;
    int n0 = bid * 64;
    const float* xsf = (const float*)xsS;
    int q  = t & 31;
    int eb = t >> 5;
    float4 acc[8];
    for (int k = 0; k < 8; k++) { acc[k].x = 0.f; acc[k].y = 0.f; acc[k].z = 0.f; acc[k].w = 0.f; }
    for (int h = 0; h < 2; h++) {
        __syncthreads();
        const float4* Wsrc = (const float4*)(loop_w + h * 8192);
        for (int p = 0; p < 8; p++) WfS[p * 256 + t] = Wsrc[p * 256 + t];
        for (int p = 0; p < 4; p++) {
            int idx = p * 256 + t;
            int e = idx >> 4, c = idx & 15;
            int n = n0 + e; if (n >= N_NODES) n = N_NODES - 1;
            xsS[idx] = ((const float4*)(x + n * 128 + h * 64))[c];
        }
        __syncthreads();
        for (int i = 0; i < 64; i++) {
            float4 wv = WfS[i * 32 + q];
            for (int k = 0; k < 8; k++) {
                float xv = xsf[(eb + 8 * k) * 64 + i];
                acc[k].x += xv * wv.x;
                acc[k].y += xv * wv.y;
                acc[k].z += xv * wv.z;
                acc[k].w += xv * wv.w;
            }
        }
    }
    float4 b4 = *((const float4*)(bias + q * 4));
    for (int k = 0; k < 8; k++) {
        int n = n0 + eb + 8 * k;
        if (n < N_NODES) {
            float4 v;
            v.x = acc[k].x + b4.x;
            v.y = acc[k].y + b4.y;
            v.z = acc[k].z + b4.z;
            v.w = acc[k].w + b4.w;
            *((float4*)(out + (size_t)n * 128 + q * 4)) = v;
        }
    }
}

// ---- msg reduction: 8 rows in parallel, uint2 loads (f16), LDS tree ----
__global__ void k_msgsum(const unsigned short* msg, const int* off2, float* out)
{
    __shared__ float4 red[256];
    int n = blockIdx.x, t = threadIdx.x;
    int m0 = off2[n], m1 = off2[n + 1];
    int rp = t >> 5, c = t & 31;
    float4 a; a.x = 0.f; a.y = 0.f; a.z = 0.f; a.w = 0.f;
    for (int j = m0 + rp; j < m1; j += 8) {
        uint2 v = *(const uint2*)(msg + (size_t)j * 128 + c * 4);
        a.x += h2f((unsigned short)(v.x & 0xffff));
        a.y += h2f((unsigned short)(v.x >> 16));
        a.z += h2f((unsigned short)(v.y & 0xffff));
        a.w += h2f((unsigned short)(v.y >> 16));
    }
    red[t] = a;
    __syncthreads();
    if (t < 128) {
        float4 b = red[t + 128];
        red[t].x += b.x; red[t].y += b.y; red[t].z += b.z; red[t].w += b.w;
    }
    __syncthreads();
    if (t < 64) {
        float4 b = red[t + 64];
        red[t].x += b.x; red[t].y += b.y; red[t].z += b.z; red[t].w += b.w;
    }
    __syncthreads();
    if (t < 32) {
        float4 v = red[t], b = red[t + 32];
        v.x += b.x; v.y += b.y; v.z += b.z; v.w += b.w;
        float4 o = *(const float4*)(out + (size_t)n * 128 + t * 4);
        v.x += o.x; v.y += o.y; v.z += o.z; v.w += o.w;
        if (v.x < 0.f) v.x = 0.f;
        if (v.y < 0.f) v.y = 0.f;
        if (v.z < 0.f) v.z = 0.f;
        if (v.w < 0.f) v.w = 0.f;
        *(float4*)(out + (size_t)n * 128 + t * 4) = v;
    }
}

// ======================= fallback path (small ws) =======================

__global__ void k_wrel(const float* weight, const float* w_comp, float* W_rel)
{
    int idx = blockIdx.x * 256 + threadIdx.x;
    int r  = idx >> 14;
    int io = idx & 16383;
    float acc = 0.0f;
    for (int b = 0; b < B_BASES; b++)
        acc += w_comp[r * B_BASES + b] * weight[b * 16384 + io];
    W_rel[idx] = acc;
}

__global__ void k_zero(float* agg, int* counts, int* counts2)
{
    int idx = blockIdx.x * 256 + threadIdx.x;
    if (idx < N_NODES * 128) agg[idx] = 0.0f;
    if (idx < R_REL) counts[idx] = 0;
    if (idx < N_NODES) counts2[idx] = 0;
}

__global__ void k_hist(const int* etypes, int* counts)
{
    __shared__ int h[R_REL];
    int t = threadIdx.x;
    if (t < R_REL) h[t] = 0;
    __syncthreads();
    int e = blockIdx.x * 256 + t;
    atomicAdd(&h[etypes[e]], 1);
    __syncthreads();
    if (t < R_REL && h[t] != 0) atomicAdd(&counts[t], h[t]);
}

__global__ void k_scan(const int* counts, int* offsets, int* cursor, int* co)
{
    if (threadIdx.x == 0) {
        int run = 0, c = 0;
        for (int r = 0; r < R_REL; r++) {
            offsets[r] = run; cursor[r] = run; co[r] = c;
            run += counts[r];
            c   += (counts[r] + 63) >> 6;
        }
        offsets[R_REL] = run; co[R_REL] = c;
    }
}

__global__ void k_scatter(const int* etypes, int* cursor, int* perm)
{
    __shared__ int h[R_REL];
    __shared__ int base[R_REL];
    int t = threadIdx.x;
    if (t < R_REL) h[t] = 0;
    __syncthreads();
    int e = blockIdx.x * 256 + t;
    int et = etypes[e];
    int rank = atomicAdd(&h[et], 1);
    __syncthreads();
    if (t < R_REL && h[t] != 0) base[t] = atomicAdd(&cursor[t], h[t]);
    __syncthreads();
    perm[base[et] + rank] = e;
}

__global__ void k_edge_atomic(const float* x, const float* W_rel, const float* norm,
                              const int* src, const int* dst, const int* perm,
                              const int* offsets, const int* co, float* agg)
{
    __shared__ float4 WfS[2048];
    __shared__ float4 xsS[1024];
    __shared__ int coS[R_REL + 1];
    __shared__ int srcS[64], dstS[64];
    __shared__ float normS[64];
    int t = threadIdx.x, bid = blockIdx.x;
    if (t <= R_REL) coS[t] = co[t];
    __syncthreads();
    if (bid >= coS[R_REL]) return;
    int r = 0;
    while (bid >= coS[r + 1]) r++;
    int e0 = offsets[r] + (bid - coS[r]) * 64;
    int cnt = offsets[r + 1] - e0;
    if (cnt > 64) cnt = 64;
    if (t < 64) {
        if (t < cnt) {
            int eid = perm[e0 + t];
            srcS[t] = src[eid]; dstS[t] = dst[eid]; normS[t] = norm[eid];
        } else { srcS[t] = 0; dstS[t] = 0; normS[t] = 0.0f; }
    }
    const float* xsf = (const float*)xsS;
    int q  = t & 31;
    int eb = t >> 5;
    float4 acc[8];
    for (int k = 0; k < 8; k++) { acc[k].x = 0.f; acc[k].y = 0.f; acc[k].z = 0.f; acc[k].w = 0.f; }
    for (int h = 0; h < 2; h++) {
        __syncthreads();
        const float4* Wsrc = (const float4*)(W_rel + r * 16384 + h * 8192);
        for (int p = 0; p < 8; p++) WfS[p * 256 + t] = Wsrc[p * 256 + t];
        for (int p = 0; p < 4; p++) {
            int idx = p * 256 + t;
            int e = idx >> 4, c = idx & 15;
            xsS[idx] = ((const float4*)(x + srcS[e] * 128 + h * 64))[c];
        }
        __syncthreads();
        for (int i = 0; i < 64; i++) {
            float4 wv = WfS[i * 32 + q];
            for (int k = 0; k < 8; k++) {
                float xv = xsf[(eb + 8 * k) * 64 + i];
                acc[k].x += xv * wv.x;
                acc[k].y += xv * wv.y;
                acc[k].z += xv * wv.z;
                acc[k].w += xv * wv.w;
            }
        }
    }
    for (int k = 0; k < 8; k++) {
        int e = eb + 8 * k;
        if (e < cnt) {
            float nrm = normS[e];
            float* row = agg + dstS[e] * 128 + q * 4;
            atomicAdd(row + 0, acc[k].x * nrm);
            atomicAdd(row + 1, acc[k].y * nrm);
            atomicAdd(row + 2, acc[k].z * nrm);
            atomicAdd(row + 3, acc[k].w * nrm);
        }
    }
}

__global__ void k_out(const float* x, const float* loop_w, const float* agg,
                      const float* bias, float* out)
{
    __shared__ float xrow[128];
    int n = blockIdx.x;
    int o = threadIdx.x;
    xrow[o] = x[n * 128 + o];
    __syncthreads();
    float acc = 0.0f;
    for (int i = 0; i < 128; i++)
        acc += xrow[i] * loop_w[i * 128 + o];
    float val = acc + agg[n * 128 + o] + bias[o];
    if (val < 0.0f) val = 0.0f;
    out[n * 128 + o] = val;
}

extern "C" void kernel_launch(void* const* d_in, const int* in_sizes, int n_in,
                              void* d_out, int out_size, void* d_ws, size_t ws_size,
                              hipStream_t stream)
{
    const float* x      = (const float*)d_in[0];
    const float* weight = (const float*)d_in[1];
    const float* w_comp = (const float*)d_in[2];
    const float* h_bias = (const float*)d_in[3];
    const float* loop_w = (const float*)d_in[4];
    const float* norm   = (const float*)d_in[5];
    const int* src    = (const int*)d_in[6];
    const int* dst    = (const int*)d_in[7];
    const int* etypes = (const int*)d_in[8];
    float* out = (float*)d_out;

    char* ws = (char*)d_ws;
    size_t off = 0;
    float* W_rel = (float*)(ws + off); off += (size_t)R_REL * 16384 * 4;      // big: wt_h plane (2MB of 4MB)
    float* agg   = (float*)(ws + off); off += (size_t)N_NODES * 128 * 4;      // big: xh plane (5MB of 10MB)
    int* perm    = (int*)(ws + off);   off += (size_t)E_EDGES * 4;
    int* counts  = (int*)(ws + off);   off += 64 * 4;
    int* offsets = (int*)(ws + off);   off += 68 * 4;
    int* cursor  = (int*)(ws + off);   off += 64 * 4;
    int* co      = (int*)(ws + off);   off += 68 * 4;
    int* counts2 = (int*)(ws + off);   off += (size_t)N_NODES * 4;
    int* off2    = (int*)(ws + off);   off += (size_t)(N_NODES + 4) * 4;      // padded to keep 16B align
    int* cursor2 = (int*)(ws + off);   off += (size_t)N_NODES * 4;
    int* pos2    = (int*)(ws + off);   off += (size_t)E_EDGES * 4;
    unsigned short* msg = (unsigned short*)(ws + off);
    size_t need_big = off + (size_t)E_EDGES * 128 * 2;
    int big = (ws_size >= need_big) ? 1 : 0;

    if (big) {
        // overlays (big path only): f16 Wt plane on W_rel slot, f16 x plane on agg slot
        unsigned short* wt_h = (unsigned short*)W_rel;
        unsigned short* xh   = (unsigned short*)agg;

        k_zero_small<<<(N_NODES + 255) / 256, 256, 0, stream>>>(counts, counts2);
        k_wrelh<<<R_REL * 16, 256, 0, stream>>>(weight, w_comp, wt_h);
        k_xhalf<<<(N_NODES * 128 / 4) / 256, 256, 0, stream>>>(x, xh);
        k_hist_all<<<E_EDGES / 256, 256, 0, stream>>>(etypes, dst, counts, counts2);
        k_scan_all<<<1, 1024, 0, stream>>>(counts, counts2, offsets, cursor, co, off2, cursor2);
        k_scatter2<<<E_EDGES / 256, 256, 0, stream>>>(etypes, dst, cursor, cursor2, perm, pos2);
        k_edge_mfma<<<E_EDGES / 64 + R_REL, 256, 0, stream>>>(
            xh, wt_h, norm, src, perm, pos2, offsets, co, msg);
        k_selfgemm<<<(N_NODES + 63) / 64, 256, 0, stream>>>(x, loop_w, h_bias, out);
        k_msgsum<<<N_NODES, 256, 0, stream>>>(msg, off2, out);
    } else {
        k_wrel<<<(R_REL * 16384) / 256, 256, 0, stream>>>(weight, w_comp, W_rel);
        k_zero<<<(N_NODES * 128) / 256, 256, 0, stream>>>(agg, counts, counts2);
        k_hist<<<E_EDGES / 256, 256, 0, stream>>>(etypes, counts);
        k_scan<<<1, 64, 0, stream>>>(counts, offsets, cursor, co);
        k_scatter<<<E_EDGES / 256, 256, 0, stream>>>(etypes, cursor, perm);
        k_edge_atomic<<<E_EDGES / 64 + R_REL, 256, 0, stream>>>(
            x, W_rel, norm, src, dst, perm, offsets, co, agg);
        k_out<<<N_NODES, 128, 0, stream>>>(x, loop_w, agg, h_bias, out);
    }
}

// Round 3
// 394.049 us; speedup vs baseline: 1.7028x; 1.0400x over previous
//
#include <hip/hip_runtime.h>

#define N_NODES 20000
#define E_EDGES 640000
#define R_REL   64
#define B_BASES 16

typedef __attribute__((ext_vector_type(4))) float f32x4;
typedef __attribute__((ext_vector_type(8))) _Float16 half8;

__device__ inline float h2f(unsigned short v) {
    _Float16 h; __builtin_memcpy(&h, &v, 2); return (float)h;
}
__device__ inline unsigned short f2h(float f) {
    _Float16 h = (_Float16)f; unsigned short v; __builtin_memcpy(&v, &h, 2); return v;
}

__device__ inline void gld_lds16(const void* g, void* l) {
    __builtin_amdgcn_global_load_lds(
        (const __attribute__((address_space(1))) void*)g,
        (__attribute__((address_space(3))) void*)l, 16, 0, 0);
}

// ======================= big-path precompute =======================

// wt_h[r][o][i] = f16( sum_b w_comp[r,b] * weight[b][i][o] )  (fused compose+transpose)
__global__ void k_wrelh(const float* weight, const float* w_comp, unsigned short* wt_h)
{
    __shared__ float tile[32][33];
    __shared__ float wcS[B_BASES];
    int r  = blockIdx.x >> 4;
    int ti = (blockIdx.x >> 2) & 3;   // i tile
    int tj = blockIdx.x & 3;          // o tile
    int tx = threadIdx.x & 31, ty = threadIdx.x >> 5;   // 32 x 8
    if (threadIdx.x < B_BASES) wcS[threadIdx.x] = w_comp[r * B_BASES + threadIdx.x];
    __syncthreads();
    float acc[4] = {0.f, 0.f, 0.f, 0.f};
    const float* wp = weight + (ti * 32) * 128 + tj * 32;
    for (int b = 0; b < B_BASES; b++) {
        float c = wcS[b];
        #pragma unroll
        for (int s = 0; s < 4; s++)
            acc[s] += c * wp[b * 16384 + (ty + s * 8) * 128 + tx];
    }
    #pragma unroll
    for (int s = 0; s < 4; s++) tile[ty + s * 8][tx] = acc[s];   // [i_local][o_local]
    __syncthreads();
    unsigned short* dstp = wt_h + r * 16384 + (tj * 32) * 128 + ti * 32;
    #pragma unroll
    for (int s = 0; s < 4; s++)
        dstp[(ty + s * 8) * 128 + tx] = f2h(tile[tx][ty + s * 8]);
}

// x -> f16
__global__ void k_xhalf(const float* x, unsigned short* xh)
{
    int i4 = blockIdx.x * 256 + threadIdx.x;   // over N*128/4
    float4 v = ((const float4*)x)[i4];
    ushort4 o;
    o.x = f2h(v.x); o.y = f2h(v.y); o.z = f2h(v.z); o.w = f2h(v.w);
    ((ushort4*)xh)[i4] = o;
}

// zero counts (64) + counts2 (20000)
__global__ void k_zero_small(int* counts, int* counts2)
{
    int idx = blockIdx.x * 256 + threadIdx.x;
    if (idx < R_REL) counts[idx] = 0;
    if (idx < N_NODES) counts2[idx] = 0;
}

// one pass over E: etype hist (LDS) + dst hist (global atomics)
__global__ void k_hist_all(const int* etypes, const int* dst, int* counts, int* counts2)
{
    __shared__ int h[R_REL];
    int t = threadIdx.x;
    if (t < R_REL) h[t] = 0;
    __syncthreads();
    int e = blockIdx.x * 256 + t;
    atomicAdd(&h[etypes[e]], 1);
    atomicAdd(&counts2[dst[e]], 1);
    __syncthreads();
    if (t < R_REL && h[t] != 0) atomicAdd(&counts[t], h[t]);
}

// single block, 1024 threads: wave-scan of 64 etype counts + scan of 20000 dst counts
// + chunk_info fill: chunk_info[c] = { (r<<20)|e0, cnt }
__global__ void k_scan_all(const int* counts, const int* counts2,
                           int* offsets, int* cursor, int* co,
                           int* off2, int* cursor2, int2* chunk_info)
{
    __shared__ int part[1024];
    __shared__ int offL[R_REL + 1];
    __shared__ int coL[R_REL + 1];
    int t = threadIdx.x;
    if (t < 64) {
        int c  = counts[t];
        int ch = (c + 63) >> 6;
        int s1 = c, s2 = ch;
        for (int d = 1; d < 64; d <<= 1) {
            int a1 = __shfl_up(s1, d);
            int a2 = __shfl_up(s2, d);
            if (t >= d) { s1 += a1; s2 += a2; }
        }
        offsets[t] = s1 - c; cursor[t] = s1 - c; co[t] = s2 - ch;
        offL[t] = s1 - c; coL[t] = s2 - ch;
        if (t == 63) { offsets[64] = s1; co[64] = s2; offL[64] = s1; coL[64] = s2; }
    }
    int lo_i = t * 20, hi_i = lo_i + 20;
    if (hi_i > N_NODES) hi_i = N_NODES;
    if (lo_i > N_NODES) lo_i = N_NODES;
    int s = 0;
    for (int i = lo_i; i < hi_i; i++) s += counts2[i];
    part[t] = s;
    __syncthreads();
    for (int d = 1; d < 1024; d <<= 1) {
        int v = (t >= d) ? part[t - d] : 0;
        __syncthreads();
        part[t] += v;
        __syncthreads();
    }
    int run = part[t] - s;                  // exclusive prefix
    for (int i = lo_i; i < hi_i; i++) {
        off2[i] = run; cursor2[i] = run;
        run += counts2[i];
    }
    if (t == 1023) off2[N_NODES] = run;

    // fill chunk_info (coL/offL visible via scan barriers above)
    int totc = coL[R_REL];
    for (int c = t; c < totc; c += 1024) {
        int rr = 0;
        #pragma unroll
        for (int step = 32; step >= 1; step >>= 1)
            if (rr + step < 64 && coL[rr + step] <= c) rr += step;
        int e0 = offL[rr] + (c - coL[rr]) * 64;
        int cn = offL[rr + 1] - e0; if (cn > 64) cn = 64;
        int2 v; v.x = (rr << 20) | e0; v.y = cn;
        chunk_info[c] = v;
    }
}

// bucket scatter by etype: pre-gathered src/norm + dst-sorted slot (order-independent)
__global__ void k_scatter2(const int* etypes, const int* dst, const int* src, const float* norm,
                           int* cursor, int* cursor2,
                           int* perm_src, float* pnorm, int* pos2)
{
    __shared__ int h[R_REL];
    __shared__ int base[R_REL];
    int t = threadIdx.x;
    if (t < R_REL) h[t] = 0;
    __syncthreads();
    int e = blockIdx.x * 256 + t;
    int et = etypes[e];
    int rank = atomicAdd(&h[et], 1);
    __syncthreads();
    if (t < R_REL && h[t] != 0) base[t] = atomicAdd(&cursor[t], h[t]);
    __syncthreads();
    int p = base[et] + rank;
    perm_src[p] = src[e];
    pnorm[p] = norm[e];
    int slot = atomicAdd(&cursor2[dst[e]], 1);
    pos2[p] = slot;
}

// ---- Phase A: per 64-edge chunk f16 MFMA GEMM; A from global, W in LDS,
//      direct permuted-layout stores (c' = wc*64 + lr*4 + n), no epilogue LDS ----
__global__ __launch_bounds__(256) void k_edge_mfma(
    const unsigned short* __restrict__ xh, const unsigned short* __restrict__ wt_h,
    const int* __restrict__ perm_src, const float* __restrict__ pnorm,
    const int* __restrict__ pos2, const int2* __restrict__ chunk_info,
    const int* __restrict__ co, unsigned short* __restrict__ msg)
{
    __shared__ __align__(16) char smemW[32768];   // W[r]: [o=128][16 chunks of 8 f16], swizzled
    int t = threadIdx.x, bid = blockIdx.x;
    if (bid >= co[R_REL]) return;
    int2 ci = chunk_info[bid];
    int r   = ci.x >> 20;
    int e0  = ci.x & 0xFFFFF;
    int cnt = ci.y;

    // stage W (32KB) via global_load_lds, pre-swizzled source, linear dest
    {
        const size_t rbase = (size_t)r * 16384;
        #pragma unroll
        for (int it = 0; it < 8; it++) {
            int s = it * 256 + t;
            int o = s >> 4, ch = s & 15;
            int j = ch ^ (o & 15);
            gld_lds16(wt_h + rbase + o * 128 + j * 8, smemW + s * 16);
        }
    }

    int l  = t & 63, w = t >> 6;
    int lg = l >> 4, lr = l & 15;
    int wr = w >> 1, wc = w & 1;        // wave -> (row-half, col-half) of 64x128

    // A fragments straight from global f16 x rows (predicated on row<cnt)
    int rowA0 = wr * 32 + lr, rowA1 = rowA0 + 16;
    int sA0 = (rowA0 < cnt) ? perm_src[e0 + rowA0] : 0;
    int sA1 = (rowA1 < cnt) ? perm_src[e0 + rowA1] : 0;
    const half8* xr0 = (const half8*)(xh + (size_t)sA0 * 128);
    const half8* xr1 = (const half8*)(xh + (size_t)sA1 * 128);
    half8 av0[4], av1[4];
    #pragma unroll
    for (int kk = 0; kk < 4; kk++) {
        av0[kk] = xr0[kk * 4 + lg];
        av1[kk] = xr1[kk * 4 + lg];
    }

    // C-row store metadata: rows wr*32 + a*16 + lg*4 + jj
    int slotC[2][4]; float nrmC[2][4];
    #pragma unroll
    for (int a = 0; a < 2; a++)
        #pragma unroll
        for (int jj = 0; jj < 4; jj++) {
            int row = wr * 32 + a * 16 + lg * 4 + jj;
            bool vld = row < cnt;
            slotC[a][jj] = vld ? pos2[e0 + row] : -1;
            nrmC[a][jj]  = vld ? pnorm[e0 + row] : 0.0f;
        }

    f32x4 acc[2][4];
    #pragma unroll
    for (int a = 0; a < 2; a++)
        #pragma unroll
        for (int n = 0; n < 4; n++)
            acc[a][n] = {0.0f, 0.0f, 0.0f, 0.0f};

    __syncthreads();   // W resident (compiler drains vmcnt before barrier)

    const half8* smW = (const half8*)smemW;
    #pragma unroll
    for (int kk = 0; kk < 4; kk++) {
        #pragma unroll
        for (int n = 0; n < 4; n++) {
            int o = wc * 64 + n * 16 + lr;
            half8 bv = smW[o * 16 + ((kk * 4 + lg) ^ (o & 15))];
            acc[0][n] = __builtin_amdgcn_mfma_f32_16x16x32_f16(av0[kk], bv, acc[0][n], 0, 0, 0);
            acc[1][n] = __builtin_amdgcn_mfma_f32_16x16x32_f16(av1[kk], bv, acc[1][n], 0, 0, 0);
        }
    }

    // direct stores: lane's 4 n-values contiguous at c' = wc*64 + lr*4 + n (8B per C-row)
    #pragma unroll
    for (int a = 0; a < 2; a++)
        #pragma unroll
        for (int jj = 0; jj < 4; jj++) {
            int slot = slotC[a][jj];
            if (slot >= 0) {
                float nm = nrmC[a][jj];
                unsigned int p0 = (unsigned int)f2h(acc[a][0][jj] * nm)
                                | ((unsigned int)f2h(acc[a][1][jj] * nm) << 16);
                unsigned int p1 = (unsigned int)f2h(acc[a][2][jj] * nm)
                                | ((unsigned int)f2h(acc[a][3][jj] * nm) << 16);
                uint2 ov; ov.x = p0; ov.y = p1;
                *(uint2*)(msg + (size_t)slot * 128 + wc * 64 + lr * 4) = ov;
            }
        }
}

// ---- self-loop GEMM: out[n][o] = x[n]@loop_w[:,o] + bias[o]  (f32, no relu yet) ----
__global__ void k_selfgemm(const float* x, const float* loop_w, const float* bias,
                           float* out)
{
    __shared__ float4 WfS[2048];     // [i=64][o/4=32]
    __shared__ float4 xsS[1024];     // [n=64][i/4=16]
    int t = threadIdx.x, bid = blockIdx.x;
    int n0 = bid * 64;
    const float* xsf = (const float*)xsS;
    int q  = t & 31;
    int eb = t >> 5;
    float4 acc[8];
    for (int k = 0; k < 8; k++) { acc[k].x = 0.f; acc[k].y = 0.f; acc[k].z = 0.f; acc[k].w = 0.f; }
    for (int h = 0; h < 2; h++) {
        __syncthreads();
        const float4* Wsrc = (const float4*)(loop_w + h * 8192);
        for (int p = 0; p < 8; p++) WfS[p * 256 + t] = Wsrc[p * 256 + t];
        for (int p = 0; p < 4; p++) {
            int idx = p * 256 + t;
            int e = idx >> 4, c = idx & 15;
            int n = n0 + e; if (n >= N_NODES) n = N_NODES - 1;
            xsS[idx] = ((const float4*)(x + n * 128 + h * 64))[c];
        }
        __syncthreads();
        for (int i = 0; i < 64; i++) {
            float4 wv = WfS[i * 32 + q];
            for (int k = 0; k < 8; k++) {
                float xv = xsf[(eb + 8 * k) * 64 + i];
                acc[k].x += xv * wv.x;
                acc[k].y += xv * wv.y;
                acc[k].z += xv * wv.z;
                acc[k].w += xv * wv.w;
            }
        }
    }
    float4 b4 = *((const float4*)(bias + q * 4));
    for (int k = 0; k < 8; k++) {
        int n = n0 + eb + 8 * k;
        if (n < N_NODES) {
            float4 v;
            v.x = acc[k].x + b4.x;
            v.y = acc[k].y + b4.y;
            v.z = acc[k].z + b4.z;
            v.w = acc[k].w + b4.w;
            *((float4*)(out + (size_t)n * 128 + q * 4)) = v;
        }
    }
}

// ---- msg reduction: permuted-layout decode, 8 rows parallel, LDS tree,
//      final un-permute via 512B LDS exchange, coalesced out ----
__global__ void k_msgsum(const unsigned short* msg, const int* off2, float* out)
{
    __shared__ float4 red[256];
    __shared__ float fin[128];
    int n = blockIdx.x, t = threadIdx.x;
    int m0 = off2[n], m1 = off2[n + 1];
    int rp = t >> 5, c = t & 31;
    float4 a; a.x = 0.f; a.y = 0.f; a.z = 0.f; a.w = 0.f;
    for (int j = m0 + rp; j < m1; j += 8) {
        uint2 v = *(const uint2*)(msg + (size_t)j * 128 + c * 4);
        a.x += h2f((unsigned short)(v.x & 0xffff));   // n=0
        a.y += h2f((unsigned short)(v.x >> 16));      // n=1
        a.z += h2f((unsigned short)(v.y & 0xffff));   // n=2
        a.w += h2f((unsigned short)(v.y >> 16));      // n=3
    }
    red[t] = a;
    __syncthreads();
    if (t < 128) {
        float4 b = red[t + 128];
        red[t].x += b.x; red[t].y += b.y; red[t].z += b.z; red[t].w += b.w;
    }
    __syncthreads();
    if (t < 64) {
        float4 b = red[t + 64];
        red[t].x += b.x; red[t].y += b.y; red[t].z += b.z; red[t].w += b.w;
    }
    __syncthreads();
    if (t < 32) {
        float4 v = red[t], b = red[t + 32];
        v.x += b.x; v.y += b.y; v.z += b.z; v.w += b.w;
        // natural col for (c=t, n) = (t>>4)*64 + n*16 + (t&15)
        int base = (t >> 4) * 64 + (t & 15);
        fin[base]      = v.x;
        fin[base + 16] = v.y;
        fin[base + 32] = v.z;
        fin[base + 48] = v.w;
    }
    __syncthreads();
    if (t < 32) {
        float4 f = ((const float4*)fin)[t];
        float4 o = *(const float4*)(out + (size_t)n * 128 + t * 4);
        f.x += o.x; f.y += o.y; f.z += o.z; f.w += o.w;
        if (f.x < 0.f) f.x = 0.f;
        if (f.y < 0.f) f.y = 0.f;
        if (f.z < 0.f) f.z = 0.f;
        if (f.w < 0.f) f.w = 0.f;
        *(float4*)(out + (size_t)n * 128 + t * 4) = f;
    }
}

// ======================= fallback path (small ws) =======================

__global__ void k_wrel(const float* weight, const float* w_comp, float* W_rel)
{
    int idx = blockIdx.x * 256 + threadIdx.x;
    int r  = idx >> 14;
    int io = idx & 16383;
    float acc = 0.0f;
    for (int b = 0; b < B_BASES; b++)
        acc += w_comp[r * B_BASES + b] * weight[b * 16384 + io];
    W_rel[idx] = acc;
}

__global__ void k_zero(float* agg, int* counts, int* counts2)
{
    int idx = blockIdx.x * 256 + threadIdx.x;
    if (idx < N_NODES * 128) agg[idx] = 0.0f;
    if (idx < R_REL) counts[idx] = 0;
    if (idx < N_NODES) counts2[idx] = 0;
}

__global__ void k_hist(const int* etypes, int* counts)
{
    __shared__ int h[R_REL];
    int t = threadIdx.x;
    if (t < R_REL) h[t] = 0;
    __syncthreads();
    int e = blockIdx.x * 256 + t;
    atomicAdd(&h[etypes[e]], 1);
    __syncthreads();
    if (t < R_REL && h[t] != 0) atomicAdd(&counts[t], h[t]);
}

__global__ void k_scan(const int* counts, int* offsets, int* cursor, int* co)
{
    if (threadIdx.x == 0) {
        int run = 0, c = 0;
        for (int r = 0; r < R_REL; r++) {
            offsets[r] = run; cursor[r] = run; co[r] = c;
            run += counts[r];
            c   += (counts[r] + 63) >> 6;
        }
        offsets[R_REL] = run; co[R_REL] = c;
    }
}

__global__ void k_scatter(const int* etypes, int* cursor, int* perm)
{
    __shared__ int h[R_REL];
    __shared__ int base[R_REL];
    int t = threadIdx.x;
    if (t < R_REL) h[t] = 0;
    __syncthreads();
    int e = blockIdx.x * 256 + t;
    int et = etypes[e];
    int rank = atomicAdd(&h[et], 1);
    __syncthreads();
    if (t < R_REL && h[t] != 0) base[t] = atomicAdd(&cursor[t], h[t]);
    __syncthreads();
    perm[base[et] + rank] = e;
}

__global__ void k_edge_atomic(const float* x, const float* W_rel, const float* norm,
                              const int* src, const int* dst, const int* perm,
                              const int* offsets, const int* co, float* agg)
{
    __shared__ float4 WfS[2048];
    __shared__ float4 xsS[1024];
    __shared__ int coS[R_REL + 1];
    __shared__ int srcS[64], dstS[64];
    __shared__ float normS[64];
    int t = threadIdx.x, bid = blockIdx.x;
    if (t <= R_REL) coS[t] = co[t];
    __syncthreads();
    if (bid >= coS[R_REL]) return;
    int r = 0;
    while (bid >= coS[r + 1]) r++;
    int e0 = offsets[r] + (bid - coS[r]) * 64;
    int cnt = offsets[r + 1] - e0;
    if (cnt > 64) cnt = 64;
    if (t < 64) {
        if (t < cnt) {
            int eid = perm[e0 + t];
            srcS[t] = src[eid]; dstS[t] = dst[eid]; normS[t] = norm[eid];
        } else { srcS[t] = 0; dstS[t] = 0; normS[t] = 0.0f; }
    }
    const float* xsf = (const float*)xsS;
    int q  = t & 31;
    int eb = t >> 5;
    float4 acc[8];
    for (int k = 0; k < 8; k++) { acc[k].x = 0.f; acc[k].y = 0.f; acc[k].z = 0.f; acc[k].w = 0.f; }
    for (int h = 0; h < 2; h++) {
        __syncthreads();
        const float4* Wsrc = (const float4*)(W_rel + r * 16384 + h * 8192);
        for (int p = 0; p < 8; p++) WfS[p * 256 + t] = Wsrc[p * 256 + t];
        for (int p = 0; p < 4; p++) {
            int idx = p * 256 + t;
            int e = idx >> 4, c = idx & 15;
            xsS[idx] = ((const float4*)(x + srcS[e] * 128 + h * 64))[c];
        }
        __syncthreads();
        for (int i = 0; i < 64; i++) {
            float4 wv = WfS[i * 32 + q];
            for (int k = 0; k < 8; k++) {
                float xv = xsf[(eb + 8 * k) * 64 + i];
                acc[k].x += xv * wv.x;
                acc[k].y += xv * wv.y;
                acc[k].z += xv * wv.z;
                acc[k].w += xv * wv.w;
            }
        }
    }
    for (int k = 0; k < 8; k++) {
        int e = eb + 8 * k;
        if (e < cnt) {
            float nrm = normS[e];
            float* row = agg + dstS[e] * 128 + q * 4;
            atomicAdd(row + 0, acc[k].x * nrm);
            atomicAdd(row + 1, acc[k].y * nrm);
            atomicAdd(row + 2, acc[k].z * nrm);
            atomicAdd(row + 3, acc[k].w * nrm);
        }
    }
}

__global__ void k_out(const float* x, const float* loop_w, const float* agg,
                      const float* bias, float* out)
{
    __shared__ float xrow[128];
    int n = blockIdx.x;
    int o = threadIdx.x;
    xrow[o] = x[n * 128 + o];
    __syncthreads();
    float acc = 0.0f;
    for (int i = 0; i < 128; i++)
        acc += xrow[i] * loop_w[i * 128 + o];
    float val = acc + agg[n * 128 + o] + bias[o];
    if (val < 0.0f) val = 0.0f;
    out[n * 128 + o] = val;
}

extern "C" void kernel_launch(void* const* d_in, const int* in_sizes, int n_in,
                              void* d_out, int out_size, void* d_ws, size_t ws_size,
                              hipStream_t stream)
{
    const float* x      = (const float*)d_in[0];
    const float* weight = (const float*)d_in[1];
    const float* w_comp = (const float*)d_in[2];
    const float* h_bias = (const float*)d_in[3];
    const float* loop_w = (const float*)d_in[4];
    const float* norm   = (const float*)d_in[5];
    const int* src    = (const int*)d_in[6];
    const int* dst    = (const int*)d_in[7];
    const int* etypes = (const int*)d_in[8];
    float* out = (float*)d_out;

    char* ws = (char*)d_ws;
    size_t off = 0;
    float* W_rel = (float*)(ws + off); off += (size_t)R_REL * 16384 * 4;      // big: wt_h (2MB) + chunk_info (80KB) in 4MB
    float* agg   = (float*)(ws + off); off += (size_t)N_NODES * 128 * 4;      // big: xh (5MB) + pnorm (2.5MB) in 10MB
    int* perm    = (int*)(ws + off);   off += (size_t)E_EDGES * 4;            // big: perm_src
    int* counts  = (int*)(ws + off);   off += 64 * 4;
    int* offsets = (int*)(ws + off);   off += 68 * 4;
    int* cursor  = (int*)(ws + off);   off += 64 * 4;
    int* co      = (int*)(ws + off);   off += 68 * 4;
    int* counts2 = (int*)(ws + off);   off += (size_t)N_NODES * 4;
    int* off2    = (int*)(ws + off);   off += (size_t)(N_NODES + 4) * 4;      // padded to keep 16B align
    int* cursor2 = (int*)(ws + off);   off += (size_t)N_NODES * 4;
    int* pos2    = (int*)(ws + off);   off += (size_t)E_EDGES * 4;
    unsigned short* msg = (unsigned short*)(ws + off);
    size_t need_big = off + (size_t)E_EDGES * 128 * 2;
    int big = (ws_size >= need_big) ? 1 : 0;

    if (big) {
        // overlays (big path only)
        unsigned short* wt_h = (unsigned short*)W_rel;                         // 2MB
        int2* chunk_info = (int2*)((char*)W_rel + (size_t)2 * 1024 * 1024);    // 80KB (in W_rel's spare 2MB)
        unsigned short* xh = (unsigned short*)agg;                             // 5MB
        float* pnorm = (float*)((char*)agg + (size_t)N_NODES * 128 * 2);       // 2.5MB (in agg's spare 5MB)
        int* perm_src = perm;

        k_zero_small<<<(N_NODES + 255) / 256, 256, 0, stream>>>(counts, counts2);
        k_wrelh<<<R_REL * 16, 256, 0, stream>>>(weight, w_comp, wt_h);
        k_xhalf<<<(N_NODES * 128 / 4) / 256, 256, 0, stream>>>(x, xh);
        k_hist_all<<<E_EDGES / 256, 256, 0, stream>>>(etypes, dst, counts, counts2);
        k_scan_all<<<1, 1024, 0, stream>>>(counts, counts2, offsets, cursor, co, off2, cursor2, chunk_info);
        k_scatter2<<<E_EDGES / 256, 256, 0, stream>>>(etypes, dst, src, norm,
                                                      cursor, cursor2, perm_src, pnorm, pos2);
        k_edge_mfma<<<E_EDGES / 64 + R_REL, 256, 0, stream>>>(
            xh, wt_h, perm_src, pnorm, pos2, chunk_info, co, msg);
        k_selfgemm<<<(N_NODES + 63) / 64, 256, 0, stream>>>(x, loop_w, h_bias, out);
        k_msgsum<<<N_NODES, 256, 0, stream>>>(msg, off2, out);
    } else {
        k_wrel<<<(R_REL * 16384) / 256, 256, 0, stream>>>(weight, w_comp, W_rel);
        k_zero<<<(N_NODES * 128) / 256, 256, 0, stream>>>(agg, counts, counts2);
        k_hist<<<E_EDGES / 256, 256, 0, stream>>>(etypes, counts);
        k_scan<<<1, 64, 0, stream>>>(counts, offsets, cursor, co);
        k_scatter<<<E_EDGES / 256, 256, 0, stream>>>(etypes, cursor, perm);
        k_edge_atomic<<<E_EDGES / 64 + R_REL, 256, 0, stream>>>(
            x, W_rel, norm, src, dst, perm, offsets, co, agg);
        k_out<<<N_NODES, 128, 0, stream>>>(x, loop_w, agg, h_bias, out);
    }
}

// Round 4
// 387.387 us; speedup vs baseline: 1.7321x; 1.0172x over previous
//
#include <hip/hip_runtime.h>

#define N_NODES 20000
#define E_EDGES 640000
#define R_REL   64
#define B_BASES 16
#define CPAD    16   // ints per padded counter (64B line)

typedef __attribute__((ext_vector_type(4))) float f32x4;
typedef __attribute__((ext_vector_type(8))) _Float16 half8;

__device__ inline float h2f(unsigned short v) {
    _Float16 h; __builtin_memcpy(&h, &v, 2); return (float)h;
}
__device__ inline unsigned short f2h(float f) {
    _Float16 h = (_Float16)f; unsigned short v; __builtin_memcpy(&v, &h, 2); return v;
}

__device__ inline void gld_lds16(const void* g, void* l) {
    __builtin_amdgcn_global_load_lds(
        (const __attribute__((address_space(1))) void*)g,
        (__attribute__((address_space(3))) void*)l, 16, 0, 0);
}

// ======================= big-path precompute =======================

// wt_h[r][o][i] = f16( sum_b w_comp[r,b] * weight[b][i][o] )  (fused compose+transpose)
__global__ void k_wrelh(const float* weight, const float* w_comp, unsigned short* wt_h)
{
    __shared__ float tile[32][33];
    __shared__ float wcS[B_BASES];
    int r  = blockIdx.x >> 4;
    int ti = (blockIdx.x >> 2) & 3;   // i tile
    int tj = blockIdx.x & 3;          // o tile
    int tx = threadIdx.x & 31, ty = threadIdx.x >> 5;   // 32 x 8
    if (threadIdx.x < B_BASES) wcS[threadIdx.x] = w_comp[r * B_BASES + threadIdx.x];
    __syncthreads();
    float acc[4] = {0.f, 0.f, 0.f, 0.f};
    const float* wp = weight + (ti * 32) * 128 + tj * 32;
    for (int b = 0; b < B_BASES; b++) {
        float c = wcS[b];
        #pragma unroll
        for (int s = 0; s < 4; s++)
            acc[s] += c * wp[b * 16384 + (ty + s * 8) * 128 + tx];
    }
    #pragma unroll
    for (int s = 0; s < 4; s++) tile[ty + s * 8][tx] = acc[s];   // [i_local][o_local]
    __syncthreads();
    unsigned short* dstp = wt_h + r * 16384 + (tj * 32) * 128 + ti * 32;
    #pragma unroll
    for (int s = 0; s < 4; s++)
        dstp[(ty + s * 8) * 128 + tx] = f2h(tile[tx][ty + s * 8]);
}

// x -> f16
__global__ void k_xhalf(const float* x, unsigned short* xh)
{
    int i4 = blockIdx.x * 256 + threadIdx.x;   // over N*128/4
    float4 v = ((const float4*)x)[i4];
    ushort4 o;
    o.x = f2h(v.x); o.y = f2h(v.y); o.z = f2h(v.z); o.w = f2h(v.w);
    ((ushort4*)xh)[i4] = o;
}

// zero padded counts (64, stride CPAD) + counts2 (20000)
__global__ void k_zero_small(int* counts_p, int* counts2)
{
    int idx = blockIdx.x * 256 + threadIdx.x;
    if (idx < R_REL) counts_p[idx * CPAD] = 0;
    if (idx < N_NODES) counts2[idx] = 0;
}

// one pass over E: etype hist (LDS, padded flush) + dst hist (global atomics)
__global__ void k_hist_all(const int* etypes, const int* dst, int* counts_p, int* counts2)
{
    __shared__ int h[R_REL];
    int t = threadIdx.x;
    if (t < R_REL) h[t] = 0;
    __syncthreads();
    int e = blockIdx.x * 256 + t;
    atomicAdd(&h[etypes[e]], 1);
    atomicAdd(&counts2[dst[e]], 1);
    __syncthreads();
    if (t < R_REL && h[t] != 0) atomicAdd(&counts_p[t * CPAD], h[t]);
}

// single block, 1024 threads: wave-scan of 64 etype counts + scan of 20000 dst counts
// + chunk_info fill: chunk_info[c] = { (r<<20)|e0, cnt }
__global__ void k_scan_all(const int* counts_p, const int* counts2,
                           int* offsets, int* cursor_p, int* co,
                           int* off2, int* cursor2, int2* chunk_info)
{
    __shared__ int part[1024];
    __shared__ int offL[R_REL + 1];
    __shared__ int coL[R_REL + 1];
    int t = threadIdx.x;
    if (t < 64) {
        int c  = counts_p[t * CPAD];
        int ch = (c + 63) >> 6;
        int s1 = c, s2 = ch;
        for (int d = 1; d < 64; d <<= 1) {
            int a1 = __shfl_up(s1, d);
            int a2 = __shfl_up(s2, d);
            if (t >= d) { s1 += a1; s2 += a2; }
        }
        offsets[t] = s1 - c; cursor_p[t * CPAD] = s1 - c; co[t] = s2 - ch;
        offL[t] = s1 - c; coL[t] = s2 - ch;
        if (t == 63) { offsets[64] = s1; co[64] = s2; offL[64] = s1; coL[64] = s2; }
    }
    int lo_i = t * 20, hi_i = lo_i + 20;
    if (hi_i > N_NODES) hi_i = N_NODES;
    if (lo_i > N_NODES) lo_i = N_NODES;
    int s = 0;
    for (int i = lo_i; i < hi_i; i++) s += counts2[i];
    part[t] = s;
    __syncthreads();
    for (int d = 1; d < 1024; d <<= 1) {
        int v = (t >= d) ? part[t - d] : 0;
        __syncthreads();
        part[t] += v;
        __syncthreads();
    }
    int run = part[t] - s;                  // exclusive prefix
    for (int i = lo_i; i < hi_i; i++) {
        off2[i] = run; cursor2[i] = run;
        run += counts2[i];
    }
    if (t == 1023) off2[N_NODES] = run;

    // fill chunk_info (coL/offL visible via scan barriers above)
    int totc = coL[R_REL];
    for (int c = t; c < totc; c += 1024) {
        int rr = 0;
        #pragma unroll
        for (int step = 32; step >= 1; step >>= 1)
            if (rr + step < 64 && coL[rr + step] <= c) rr += step;
        int e0 = offL[rr] + (c - coL[rr]) * 64;
        int cn = offL[rr + 1] - e0; if (cn > 64) cn = 64;
        int2 v; v.x = (rr << 20) | e0; v.y = cn;
        chunk_info[c] = v;
    }
}

// bucket scatter by etype: pre-gathered src/norm + dst-sorted slot (order-independent)
__global__ void k_scatter2(const int* etypes, const int* dst, const int* src, const float* norm,
                           int* cursor_p, int* cursor2,
                           int* perm_src, float* pnorm, int* pos2)
{
    __shared__ int h[R_REL];
    __shared__ int base[R_REL];
    int t = threadIdx.x;
    if (t < R_REL) h[t] = 0;
    __syncthreads();
    int e = blockIdx.x * 256 + t;
    int et = etypes[e];
    int rank = atomicAdd(&h[et], 1);
    __syncthreads();
    if (t < R_REL && h[t] != 0) base[t] = atomicAdd(&cursor_p[t * CPAD], h[t]);
    __syncthreads();
    int p = base[et] + rank;
    perm_src[p] = src[e];
    pnorm[p] = norm[e];
    int slot = atomicAdd(&cursor2[dst[e]], 1);
    pos2[p] = slot;
}

// ---- Phase A: per 64-edge chunk f16 MFMA GEMM; A from global, W in LDS,
//      direct permuted-layout stores (c' = wc*64 + lr*4 + n), no epilogue LDS ----
__global__ __launch_bounds__(256) void k_edge_mfma(
    const unsigned short* __restrict__ xh, const unsigned short* __restrict__ wt_h,
    const int* __restrict__ perm_src, const float* __restrict__ pnorm,
    const int* __restrict__ pos2, const int2* __restrict__ chunk_info,
    const int* __restrict__ co, unsigned short* __restrict__ msg)
{
    __shared__ __align__(16) char smemW[32768];   // W[r]: [o=128][16 chunks of 8 f16], swizzled
    int t = threadIdx.x, bid = blockIdx.x;
    if (bid >= co[R_REL]) return;
    int2 ci = chunk_info[bid];
    int r   = ci.x >> 20;
    int e0  = ci.x & 0xFFFFF;
    int cnt = ci.y;

    // stage W (32KB) via global_load_lds, pre-swizzled source, linear dest
    {
        const size_t rbase = (size_t)r * 16384;
        #pragma unroll
        for (int it = 0; it < 8; it++) {
            int s = it * 256 + t;
            int o = s >> 4, ch = s & 15;
            int j = ch ^ (o & 15);
            gld_lds16(wt_h + rbase + o * 128 + j * 8, smemW + s * 16);
        }
    }

    int l  = t & 63, w = t >> 6;
    int lg = l >> 4, lr = l & 15;
    int wr = w >> 1, wc = w & 1;        // wave -> (row-half, col-half) of 64x128

    // A fragments straight from global f16 x rows (predicated on row<cnt)
    int rowA0 = wr * 32 + lr, rowA1 = rowA0 + 16;
    int sA0 = (rowA0 < cnt) ? perm_src[e0 + rowA0] : 0;
    int sA1 = (rowA1 < cnt) ? perm_src[e0 + rowA1] : 0;
    const half8* xr0 = (const half8*)(xh + (size_t)sA0 * 128);
    const half8* xr1 = (const half8*)(xh + (size_t)sA1 * 128);
    half8 av0[4], av1[4];
    #pragma unroll
    for (int kk = 0; kk < 4; kk++) {
        av0[kk] = xr0[kk * 4 + lg];
        av1[kk] = xr1[kk * 4 + lg];
    }

    // C-row store metadata: rows wr*32 + a*16 + lg*4 + jj
    int slotC[2][4]; float nrmC[2][4];
    #pragma unroll
    for (int a = 0; a < 2; a++)
        #pragma unroll
        for (int jj = 0; jj < 4; jj++) {
            int row = wr * 32 + a * 16 + lg * 4 + jj;
            bool vld = row < cnt;
            slotC[a][jj] = vld ? pos2[e0 + row] : -1;
            nrmC[a][jj]  = vld ? pnorm[e0 + row] : 0.0f;
        }

    f32x4 acc[2][4];
    #pragma unroll
    for (int a = 0; a < 2; a++)
        #pragma unroll
        for (int n = 0; n < 4; n++)
            acc[a][n] = {0.0f, 0.0f, 0.0f, 0.0f};

    __syncthreads();   // W resident (compiler drains vmcnt before barrier)

    const half8* smW = (const half8*)smemW;
    #pragma unroll
    for (int kk = 0; kk < 4; kk++) {
        #pragma unroll
        for (int n = 0; n < 4; n++) {
            int o = wc * 64 + n * 16 + lr;
            half8 bv = smW[o * 16 + ((kk * 4 + lg) ^ (o & 15))];
            acc[0][n] = __builtin_amdgcn_mfma_f32_16x16x32_f16(av0[kk], bv, acc[0][n], 0, 0, 0);
            acc[1][n] = __builtin_amdgcn_mfma_f32_16x16x32_f16(av1[kk], bv, acc[1][n], 0, 0, 0);
        }
    }

    // direct stores: lane's 4 n-values contiguous at c' = wc*64 + lr*4 + n (8B per C-row)
    #pragma unroll
    for (int a = 0; a < 2; a++)
        #pragma unroll
        for (int jj = 0; jj < 4; jj++) {
            int slot = slotC[a][jj];
            if (slot >= 0) {
                float nm = nrmC[a][jj];
                unsigned int p0 = (unsigned int)f2h(acc[a][0][jj] * nm)
                                | ((unsigned int)f2h(acc[a][1][jj] * nm) << 16);
                unsigned int p1 = (unsigned int)f2h(acc[a][2][jj] * nm)
                                | ((unsigned int)f2h(acc[a][3][jj] * nm) << 16);
                uint2 ov; ov.x = p0; ov.y = p1;
                *(uint2*)(msg + (size_t)slot * 128 + wc * 64 + lr * 4) = ov;
            }
        }
}

// ---- self-loop GEMM: out[n][o] = x[n]@loop_w[:,o] + bias[o]  (f32, no relu yet) ----
__global__ void k_selfgemm(const float* x, const float* loop_w, const float* bias,
                           float* out)
{
    __shared__ float4 WfS[2048];     // [i=64][o/4=32]
    __shared__ float4 xsS[1024];     // [n=64][i/4=16]
    int t = threadIdx.x, bid = blockIdx.x;
    int n0 = bid * 64;
    const float* xsf = (const float*)xsS;
    int q  = t & 31;
    int eb = t >> 5;
    float4 acc[8];
    for (int k = 0; k < 8; k++) { acc[k].x = 0.f; acc[k].y = 0.f; acc[k].z = 0.f; acc[k].w = 0.f; }
    for (int h = 0; h < 2; h++) {
        __syncthreads();
        const float4* Wsrc = (const float4*)(loop_w + h * 8192);
        for (int p = 0; p < 8; p++) WfS[p * 256 + t] = Wsrc[p * 256 + t];
        for (int p = 0; p < 4; p++) {
            int idx = p * 256 + t;
            int e = idx >> 4, c = idx & 15;
            int n = n0 + e; if (n >= N_NODES) n = N_NODES - 1;
            xsS[idx] = ((const float4*)(x + n * 128 + h * 64))[c];
        }
        __syncthreads();
        for (int i = 0; i < 64; i++) {
            float4 wv = WfS[i * 32 + q];
            for (int k = 0; k < 8; k++) {
                float xv = xsf[(eb + 8 * k) * 64 + i];
                acc[k].x += xv * wv.x;
                acc[k].y += xv * wv.y;
                acc[k].z += xv * wv.z;
                acc[k].w += xv * wv.w;
            }
        }
    }
    float4 b4 = *((const float4*)(bias + q * 4));
    for (int k = 0; k < 8; k++) {
        int n = n0 + eb + 8 * k;
        if (n < N_NODES) {
            float4 v;
            v.x = acc[k].x + b4.x;
            v.y = acc[k].y + b4.y;
            v.z = acc[k].z + b4.z;
            v.w = acc[k].w + b4.w;
            *((float4*)(out + (size_t)n * 128 + q * 4)) = v;
        }
    }
}

// ---- msg reduction: permuted-layout decode, 8 rows parallel, LDS tree,
//      final un-permute via 512B LDS exchange, coalesced out ----
__global__ void k_msgsum(const unsigned short* msg, const int* off2, float* out)
{
    __shared__ float4 red[256];
    __shared__ float fin[128];
    int n = blockIdx.x, t = threadIdx.x;
    int m0 = off2[n], m1 = off2[n + 1];
    int rp = t >> 5, c = t & 31;
    float4 a; a.x = 0.f; a.y = 0.f; a.z = 0.f; a.w = 0.f;
    for (int j = m0 + rp; j < m1; j += 8) {
        uint2 v = *(const uint2*)(msg + (size_t)j * 128 + c * 4);
        a.x += h2f((unsigned short)(v.x & 0xffff));   // n=0
        a.y += h2f((unsigned short)(v.x >> 16));      // n=1
        a.z += h2f((unsigned short)(v.y & 0xffff));   // n=2
        a.w += h2f((unsigned short)(v.y >> 16));      // n=3
    }
    red[t] = a;
    __syncthreads();
    if (t < 128) {
        float4 b = red[t + 128];
        red[t].x += b.x; red[t].y += b.y; red[t].z += b.z; red[t].w += b.w;
    }
    __syncthreads();
    if (t < 64) {
        float4 b = red[t + 64];
        red[t].x += b.x; red[t].y += b.y; red[t].z += b.z; red[t].w += b.w;
    }
    __syncthreads();
    if (t < 32) {
        float4 v = red[t], b = red[t + 32];
        v.x += b.x; v.y += b.y; v.z += b.z; v.w += b.w;
        // natural col for (c=t, n) = (t>>4)*64 + n*16 + (t&15)
        int base = (t >> 4) * 64 + (t & 15);
        fin[base]      = v.x;
        fin[base + 16] = v.y;
        fin[base + 32] = v.z;
        fin[base + 48] = v.w;
    }
    __syncthreads();
    if (t < 32) {
        float4 f = ((const float4*)fin)[t];
        float4 o = *(const float4*)(out + (size_t)n * 128 + t * 4);
        f.x += o.x; f.y += o.y; f.z += o.z; f.w += o.w;
        if (f.x < 0.f) f.x = 0.f;
        if (f.y < 0.f) f.y = 0.f;
        if (f.z < 0.f) f.z = 0.f;
        if (f.w < 0.f) f.w = 0.f;
        *(float4*)(out + (size_t)n * 128 + t * 4) = f;
    }
}

// ======================= fallback path (small ws) =======================

__global__ void k_wrel(const float* weight, const float* w_comp, float* W_rel)
{
    int idx = blockIdx.x * 256 + threadIdx.x;
    int r  = idx >> 14;
    int io = idx & 16383;
    float acc = 0.0f;
    for (int b = 0; b < B_BASES; b++)
        acc += w_comp[r * B_BASES + b] * weight[b * 16384 + io];
    W_rel[idx] = acc;
}

__global__ void k_zero(float* agg, int* counts, int* counts2)
{
    int idx = blockIdx.x * 256 + threadIdx.x;
    if (idx < N_NODES * 128) agg[idx] = 0.0f;
    if (idx < R_REL) counts[idx] = 0;
    if (idx < N_NODES) counts2[idx] = 0;
}

__global__ void k_hist(const int* etypes, int* counts)
{
    __shared__ int h[R_REL];
    int t = threadIdx.x;
    if (t < R_REL) h[t] = 0;
    __syncthreads();
    int e = blockIdx.x * 256 + t;
    atomicAdd(&h[etypes[e]], 1);
    __syncthreads();
    if (t < R_REL && h[t] != 0) atomicAdd(&counts[t], h[t]);
}

__global__ void k_scan(const int* counts, int* offsets, int* cursor, int* co)
{
    if (threadIdx.x == 0) {
        int run = 0, c = 0;
        for (int r = 0; r < R_REL; r++) {
            offsets[r] = run; cursor[r] = run; co[r] = c;
            run += counts[r];
            c   += (counts[r] + 63) >> 6;
        }
        offsets[R_REL] = run; co[R_REL] = c;
    }
}

__global__ void k_scatter(const int* etypes, int* cursor, int* perm)
{
    __shared__ int h[R_REL];
    __shared__ int base[R_REL];
    int t = threadIdx.x;
    if (t < R_REL) h[t] = 0;
    __syncthreads();
    int e = blockIdx.x * 256 + t;
    int et = etypes[e];
    int rank = atomicAdd(&h[et], 1);
    __syncthreads();
    if (t < R_REL && h[t] != 0) base[t] = atomicAdd(&cursor[t], h[t]);
    __syncthreads();
    perm[base[et] + rank] = e;
}

__global__ void k_edge_atomic(const float* x, const float* W_rel, const float* norm,
                              const int* src, const int* dst, const int* perm,
                              const int* offsets, const int* co, float* agg)
{
    __shared__ float4 WfS[2048];
    __shared__ float4 xsS[1024];
    __shared__ int coS[R_REL + 1];
    __shared__ int srcS[64], dstS[64];
    __shared__ float normS[64];
    int t = threadIdx.x, bid = blockIdx.x;
    if (t <= R_REL) coS[t] = co[t];
    __syncthreads();
    if (bid >= coS[R_REL]) return;
    int r = 0;
    while (bid >= coS[r + 1]) r++;
    int e0 = offsets[r] + (bid - coS[r]) * 64;
    int cnt = offsets[r + 1] - e0;
    if (cnt > 64) cnt = 64;
    if (t < 64) {
        if (t < cnt) {
            int eid = perm[e0 + t];
            srcS[t] = src[eid]; dstS[t] = dst[eid]; normS[t] = norm[eid];
        } else { srcS[t] = 0; dstS[t] = 0; normS[t] = 0.0f; }
    }
    const float* xsf = (const float*)xsS;
    int q  = t & 31;
    int eb = t >> 5;
    float4 acc[8];
    for (int k = 0; k < 8; k++) { acc[k].x = 0.f; acc[k].y = 0.f; acc[k].z = 0.f; acc[k].w = 0.f; }
    for (int h = 0; h < 2; h++) {
        __syncthreads();
        const float4* Wsrc = (const float4*)(W_rel + r * 16384 + h * 8192);
        for (int p = 0; p < 8; p++) WfS[p * 256 + t] = Wsrc[p * 256 + t];
        for (int p = 0; p < 4; p++) {
            int idx = p * 256 + t;
            int e = idx >> 4, c = idx & 15;
            xsS[idx] = ((const float4*)(x + srcS[e] * 128 + h * 64))[c];
        }
        __syncthreads();
        for (int i = 0; i < 64; i++) {
            float4 wv = WfS[i * 32 + q];
            for (int k = 0; k < 8; k++) {
                float xv = xsf[(eb + 8 * k) * 64 + i];
                acc[k].x += xv * wv.x;
                acc[k].y += xv * wv.y;
                acc[k].z += xv * wv.z;
                acc[k].w += xv * wv.w;
            }
        }
    }
    for (int k = 0; k < 8; k++) {
        int e = eb + 8 * k;
        if (e < cnt) {
            float nrm = normS[e];
            float* row = agg + dstS[e] * 128 + q * 4;
            atomicAdd(row + 0, acc[k].x * nrm);
            atomicAdd(row + 1, acc[k].y * nrm);
            atomicAdd(row + 2, acc[k].z * nrm);
            atomicAdd(row + 3, acc[k].w * nrm);
        }
    }
}

__global__ void k_out(const float* x, const float* loop_w, const float* agg,
                      const float* bias, float* out)
{
    __shared__ float xrow[128];
    int n = blockIdx.x;
    int o = threadIdx.x;
    xrow[o] = x[n * 128 + o];
    __syncthreads();
    float acc = 0.0f;
    for (int i = 0; i < 128; i++)
        acc += xrow[i] * loop_w[i * 128 + o];
    float val = acc + agg[n * 128 + o] + bias[o];
    if (val < 0.0f) val = 0.0f;
    out[n * 128 + o] = val;
}

extern "C" void kernel_launch(void* const* d_in, const int* in_sizes, int n_in,
                              void* d_out, int out_size, void* d_ws, size_t ws_size,
                              hipStream_t stream)
{
    const float* x      = (const float*)d_in[0];
    const float* weight = (const float*)d_in[1];
    const float* w_comp = (const float*)d_in[2];
    const float* h_bias = (const float*)d_in[3];
    const float* loop_w = (const float*)d_in[4];
    const float* norm   = (const float*)d_in[5];
    const int* src    = (const int*)d_in[6];
    const int* dst    = (const int*)d_in[7];
    const int* etypes = (const int*)d_in[8];
    float* out = (float*)d_out;

    char* ws = (char*)d_ws;
    size_t off = 0;
    float* W_rel = (float*)(ws + off); off += (size_t)R_REL * 16384 * 4;      // big: wt_h (2MB) + chunk_info + padded counters in 4MB
    float* agg   = (float*)(ws + off); off += (size_t)N_NODES * 128 * 4;      // big: xh (5MB) + pnorm (2.5MB) in 10MB
    int* perm    = (int*)(ws + off);   off += (size_t)E_EDGES * 4;            // big: perm_src
    int* counts  = (int*)(ws + off);   off += 64 * 4;
    int* offsets = (int*)(ws + off);   off += 68 * 4;
    int* cursor  = (int*)(ws + off);   off += 64 * 4;
    int* co      = (int*)(ws + off);   off += 68 * 4;
    int* counts2 = (int*)(ws + off);   off += (size_t)N_NODES * 4;
    int* off2    = (int*)(ws + off);   off += (size_t)(N_NODES + 4) * 4;      // padded to keep 16B align
    int* cursor2 = (int*)(ws + off);   off += (size_t)N_NODES * 4;
    int* pos2    = (int*)(ws + off);   off += (size_t)E_EDGES * 4;
    unsigned short* msg = (unsigned short*)(ws + off);
    size_t need_big = off + (size_t)E_EDGES * 128 * 2;
    int big = (ws_size >= need_big) ? 1 : 0;

    if (big) {
        // overlays (big path only), all inside W_rel/agg spare space
        unsigned short* wt_h = (unsigned short*)W_rel;                         // 2MB
        char* wspare = (char*)W_rel + (size_t)2 * 1024 * 1024;
        int2* chunk_info = (int2*)wspare;                                      // ≤96KB
        int* counts_p = (int*)(wspare + 96 * 1024);                            // 64 * 64B = 4KB
        int* cursor_p = (int*)(wspare + 100 * 1024);                           // 4KB
        unsigned short* xh = (unsigned short*)agg;                             // 5MB
        float* pnorm = (float*)((char*)agg + (size_t)N_NODES * 128 * 2);       // 2.5MB
        int* perm_src = perm;

        k_zero_small<<<(N_NODES + 255) / 256, 256, 0, stream>>>(counts_p, counts2);
        k_wrelh<<<R_REL * 16, 256, 0, stream>>>(weight, w_comp, wt_h);
        k_xhalf<<<(N_NODES * 128 / 4) / 256, 256, 0, stream>>>(x, xh);
        k_hist_all<<<E_EDGES / 256, 256, 0, stream>>>(etypes, dst, counts_p, counts2);
        k_scan_all<<<1, 1024, 0, stream>>>(counts_p, counts2, offsets, cursor_p, co, off2, cursor2, chunk_info);
        k_scatter2<<<E_EDGES / 256, 256, 0, stream>>>(etypes, dst, src, norm,
                                                      cursor_p, cursor2, perm_src, pnorm, pos2);
        k_edge_mfma<<<E_EDGES / 64 + R_REL, 256, 0, stream>>>(
            xh, wt_h, perm_src, pnorm, pos2, chunk_info, co, msg);
        k_selfgemm<<<(N_NODES + 63) / 64, 256, 0, stream>>>(x, loop_w, h_bias, out);
        k_msgsum<<<N_NODES, 256, 0, stream>>>(msg, off2, out);
    } else {
        k_wrel<<<(R_REL * 16384) / 256, 256, 0, stream>>>(weight, w_comp, W_rel);
        k_zero<<<(N_NODES * 128) / 256, 256, 0, stream>>>(agg, counts, counts2);
        k_hist<<<E_EDGES / 256, 256, 0, stream>>>(etypes, counts);
        k_scan<<<1, 64, 0, stream>>>(counts, offsets, cursor, co);
        k_scatter<<<E_EDGES / 256, 256, 0, stream>>>(etypes, cursor, perm);
        k_edge_atomic<<<E_EDGES / 64 + R_REL, 256, 0, stream>>>(
            x, W_rel, norm, src, dst, perm, offsets, co, agg);
        k_out<<<N_NODES, 128, 0, stream>>>(x, loop_w, agg, h_bias, out);
    }
}

// Round 5
// 326.063 us; speedup vs baseline: 2.0579x; 1.1881x over previous
//
#include <hip/hip_runtime.h>

#define N_NODES 20000
#define E_EDGES 640000
#define R_REL   64
#define B_BASES 16
#define NSEG    128          // edge segments
#define SEGLEN  (E_EDGES / NSEG)   // 5000
#define RH      10000        // node half-range (LDS histogram bins)

typedef __attribute__((ext_vector_type(4))) float f32x4;
typedef __attribute__((ext_vector_type(8))) _Float16 half8;

__device__ inline float h2f(unsigned short v) {
    _Float16 h; __builtin_memcpy(&h, &v, 2); return (float)h;
}
__device__ inline unsigned short f2h(float f) {
    _Float16 h = (_Float16)f; unsigned short v; __builtin_memcpy(&v, &h, 2); return v;
}

__device__ inline void gld_lds16(const void* g, void* l) {
    __builtin_amdgcn_global_load_lds(
        (const __attribute__((address_space(1))) void*)g,
        (__attribute__((address_space(3))) void*)l, 16, 0, 0);
}

// ======================= big-path precompute =======================

// wt_h[r][o][i] = f16( sum_b w_comp[r,b] * weight[b][i][o] )  (fused compose+transpose)
__global__ void k_wrelh(const float* weight, const float* w_comp, unsigned short* wt_h)
{
    __shared__ float tile[32][33];
    __shared__ float wcS[B_BASES];
    int r  = blockIdx.x >> 4;
    int ti = (blockIdx.x >> 2) & 3;   // i tile
    int tj = blockIdx.x & 3;          // o tile
    int tx = threadIdx.x & 31, ty = threadIdx.x >> 5;   // 32 x 8
    if (threadIdx.x < B_BASES) wcS[threadIdx.x] = w_comp[r * B_BASES + threadIdx.x];
    __syncthreads();
    float acc[4] = {0.f, 0.f, 0.f, 0.f};
    const float* wp = weight + (ti * 32) * 128 + tj * 32;
    for (int b = 0; b < B_BASES; b++) {
        float c = wcS[b];
        #pragma unroll
        for (int s = 0; s < 4; s++)
            acc[s] += c * wp[b * 16384 + (ty + s * 8) * 128 + tx];
    }
    #pragma unroll
    for (int s = 0; s < 4; s++) tile[ty + s * 8][tx] = acc[s];   // [i_local][o_local]
    __syncthreads();
    unsigned short* dstp = wt_h + r * 16384 + (tj * 32) * 128 + ti * 32;
    #pragma unroll
    for (int s = 0; s < 4; s++)
        dstp[(ty + s * 8) * 128 + tx] = f2h(tile[tx][ty + s * 8]);
}

// x -> f16
__global__ void k_xhalf(const float* x, unsigned short* xh)
{
    int i4 = blockIdx.x * 256 + threadIdx.x;   // over N*128/4
    float4 v = ((const float4*)x)[i4];
    ushort4 o;
    o.x = f2h(v.x); o.y = f2h(v.y); o.z = f2h(v.z); o.w = f2h(v.w);
    ((ushort4*)xh)[i4] = o;
}

// per-(seg,half) dst histogram (LDS atomics only) + etype histogram of in-range edges
// hp[s*N_NODES + h*RH + j], he[q*64 + et]  (q = s*2+h)
__global__ void k_histp(const int* etypes, const int* dst, int* hp, int* he)
{
    __shared__ int lh[RH];
    __shared__ int heL[R_REL];
    int t = threadIdx.x, q = blockIdx.x;
    int s = q >> 1, h = q & 1;
    for (int i = t; i < RH; i += 256) lh[i] = 0;
    if (t < R_REL) heL[t] = 0;
    __syncthreads();
    int e0 = s * SEGLEN;
    for (int k = t; k < SEGLEN; k += 256) {
        int e = e0 + k;
        int d = dst[e];
        unsigned ld = (unsigned)(d - h * RH);
        if (ld < RH) {
            atomicAdd(&lh[ld], 1);
            atomicAdd(&heL[etypes[e]], 1);
        }
    }
    __syncthreads();
    for (int i = t; i < RH; i += 256) hp[s * N_NODES + h * RH + i] = lh[i];
    if (t < R_REL) he[q * 64 + t] = heL[t];
}

// counts2[n] = sum over segs of hp[s][n]  (coalesced column sum, no atomics)
__global__ void k_sumc(const int* hp, int* counts2)
{
    int n = blockIdx.x * 256 + threadIdx.x;
    if (n >= N_NODES) return;
    int s = 0;
    for (int q = 0; q < NSEG; q++) s += hp[q * N_NODES + n];
    counts2[n] = s;
}

// single block 1024: etype scan (from he), off2 scan (from counts2),
// be fill (per-(seg,half,etype) bases), chunk_info fill
__global__ void k_scan_all2(const int* he, const int* counts2,
                            int* offsets, int* co, int* off2,
                            int* be, int2* chunk_info)
{
    __shared__ int part[1024];
    __shared__ int offL[R_REL + 1];
    __shared__ int coL[R_REL + 1];
    int t = threadIdx.x;
    if (t < 64) {
        int c = 0;
        for (int q = 0; q < 2 * NSEG; q++) c += he[q * 64 + t];
        int ch = (c + 63) >> 6;
        int s1 = c, s2 = ch;
        for (int d = 1; d < 64; d <<= 1) {
            int a1 = __shfl_up(s1, d);
            int a2 = __shfl_up(s2, d);
            if (t >= d) { s1 += a1; s2 += a2; }
        }
        offsets[t] = s1 - c; co[t] = s2 - ch;
        offL[t] = s1 - c; coL[t] = s2 - ch;
        if (t == 63) { offsets[64] = s1; co[64] = s2; offL[64] = s1; coL[64] = s2; }
        // per-(seg,half) etype bases
        int run = s1 - c;
        for (int q = 0; q < 2 * NSEG; q++) {
            be[q * 64 + t] = run;
            run += he[q * 64 + t];
        }
    }
    int lo_i = t * 20, hi_i = lo_i + 20;
    if (hi_i > N_NODES) hi_i = N_NODES;
    if (lo_i > N_NODES) lo_i = N_NODES;
    int s = 0;
    for (int i = lo_i; i < hi_i; i++) s += counts2[i];
    part[t] = s;
    __syncthreads();
    for (int d = 1; d < 1024; d <<= 1) {
        int v = (t >= d) ? part[t - d] : 0;
        __syncthreads();
        part[t] += v;
        __syncthreads();
    }
    int run = part[t] - s;                  // exclusive prefix
    for (int i = lo_i; i < hi_i; i++) {
        off2[i] = run;
        run += counts2[i];
    }
    if (t == 1023) off2[N_NODES] = run;

    // chunk_info (offL/coL visible to all threads via the scan barriers above)
    int totc = coL[R_REL];
    for (int c = t; c < totc; c += 1024) {
        int rr = 0;
        #pragma unroll
        for (int step = 32; step >= 1; step >>= 1)
            if (rr + step < 64 && coL[rr + step] <= c) rr += step;
        int e0 = offL[rr] + (c - coL[rr]) * 64;
        int cn = offL[rr + 1] - e0; if (cn > 64) cn = 64;
        int2 v; v.x = (rr << 20) | e0; v.y = cn;
        chunk_info[c] = v;
    }
}

// hp[s][n] -> global slot base: column-wise exclusive scan seeded by off2[n]
__global__ void k_segbase(const int* off2, int* hp)
{
    int n = blockIdx.x * 256 + threadIdx.x;
    if (n >= N_NODES) return;
    int run = off2[n];
    for (int q = 0; q < NSEG; q++) {
        int v = hp[q * N_NODES + n];
        hp[q * N_NODES + n] = run;
        run += v;
    }
}

// per-(seg,half): LDS-atomic slot + p assignment, clustered stores. No global atomics.
__global__ void k_scatter3(const int* etypes, const int* dst, const int* src, const float* norm,
                           const int* hp, const int* be,
                           int* perm_src, float* pnorm, int* pos2)
{
    __shared__ int lbase[RH];
    __shared__ int ebase[R_REL];
    int t = threadIdx.x, q = blockIdx.x;
    int s = q >> 1, h = q & 1;
    for (int i = t; i < RH; i += 256) lbase[i] = hp[s * N_NODES + h * RH + i];
    if (t < R_REL) ebase[t] = be[q * 64 + t];
    __syncthreads();
    int e0 = s * SEGLEN;
    for (int k = t; k < SEGLEN; k += 256) {
        int e = e0 + k;
        int d = dst[e];
        unsigned ld = (unsigned)(d - h * RH);
        if (ld < RH) {
            int slot = atomicAdd(&lbase[ld], 1);
            int p = atomicAdd(&ebase[etypes[e]], 1);
            perm_src[p] = src[e];
            pnorm[p] = norm[e];
            pos2[p] = slot;
        }
    }
}

// ---- Phase A: per 64-edge chunk f16 MFMA GEMM; A from global, W in LDS,
//      direct permuted-layout stores (c' = wc*64 + lr*4 + n), no epilogue LDS ----
__global__ __launch_bounds__(256) void k_edge_mfma(
    const unsigned short* __restrict__ xh, const unsigned short* __restrict__ wt_h,
    const int* __restrict__ perm_src, const float* __restrict__ pnorm,
    const int* __restrict__ pos2, const int2* __restrict__ chunk_info,
    const int* __restrict__ co, unsigned short* __restrict__ msg)
{
    __shared__ __align__(16) char smemW[32768];   // W[r]: [o=128][16 chunks of 8 f16], swizzled
    int t = threadIdx.x, bid = blockIdx.x;
    if (bid >= co[R_REL]) return;
    int2 ci = chunk_info[bid];
    int r   = ci.x >> 20;
    int e0  = ci.x & 0xFFFFF;
    int cnt = ci.y;

    // stage W (32KB) via global_load_lds, pre-swizzled source, linear dest
    {
        const size_t rbase = (size_t)r * 16384;
        #pragma unroll
        for (int it = 0; it < 8; it++) {
            int s = it * 256 + t;
            int o = s >> 4, ch = s & 15;
            int j = ch ^ (o & 15);
            gld_lds16(wt_h + rbase + o * 128 + j * 8, smemW + s * 16);
        }
    }

    int l  = t & 63, w = t >> 6;
    int lg = l >> 4, lr = l & 15;
    int wr = w >> 1, wc = w & 1;        // wave -> (row-half, col-half) of 64x128

    // A fragments straight from global f16 x rows (predicated on row<cnt)
    int rowA0 = wr * 32 + lr, rowA1 = rowA0 + 16;
    int sA0 = (rowA0 < cnt) ? perm_src[e0 + rowA0] : 0;
    int sA1 = (rowA1 < cnt) ? perm_src[e0 + rowA1] : 0;
    const half8* xr0 = (const half8*)(xh + (size_t)sA0 * 128);
    const half8* xr1 = (const half8*)(xh + (size_t)sA1 * 128);
    half8 av0[4], av1[4];
    #pragma unroll
    for (int kk = 0; kk < 4; kk++) {
        av0[kk] = xr0[kk * 4 + lg];
        av1[kk] = xr1[kk * 4 + lg];
    }

    // C-row store metadata: rows wr*32 + a*16 + lg*4 + jj
    int slotC[2][4]; float nrmC[2][4];
    #pragma unroll
    for (int a = 0; a < 2; a++)
        #pragma unroll
        for (int jj = 0; jj < 4; jj++) {
            int row = wr * 32 + a * 16 + lg * 4 + jj;
            bool vld = row < cnt;
            slotC[a][jj] = vld ? pos2[e0 + row] : -1;
            nrmC[a][jj]  = vld ? pnorm[e0 + row] : 0.0f;
        }

    f32x4 acc[2][4];
    #pragma unroll
    for (int a = 0; a < 2; a++)
        #pragma unroll
        for (int n = 0; n < 4; n++)
            acc[a][n] = {0.0f, 0.0f, 0.0f, 0.0f};

    __syncthreads();   // W resident (compiler drains vmcnt before barrier)

    const half8* smW = (const half8*)smemW;
    #pragma unroll
    for (int kk = 0; kk < 4; kk++) {
        #pragma unroll
        for (int n = 0; n < 4; n++) {
            int o = wc * 64 + n * 16 + lr;
            half8 bv = smW[o * 16 + ((kk * 4 + lg) ^ (o & 15))];
            acc[0][n] = __builtin_amdgcn_mfma_f32_16x16x32_f16(av0[kk], bv, acc[0][n], 0, 0, 0);
            acc[1][n] = __builtin_amdgcn_mfma_f32_16x16x32_f16(av1[kk], bv, acc[1][n], 0, 0, 0);
        }
    }

    // direct stores: lane's 4 n-values contiguous at c' = wc*64 + lr*4 + n (8B per C-row)
    #pragma unroll
    for (int a = 0; a < 2; a++)
        #pragma unroll
        for (int jj = 0; jj < 4; jj++) {
            int slot = slotC[a][jj];
            if (slot >= 0) {
                float nm = nrmC[a][jj];
                unsigned int p0 = (unsigned int)f2h(acc[a][0][jj] * nm)
                                | ((unsigned int)f2h(acc[a][1][jj] * nm) << 16);
                unsigned int p1 = (unsigned int)f2h(acc[a][2][jj] * nm)
                                | ((unsigned int)f2h(acc[a][3][jj] * nm) << 16);
                uint2 ov; ov.x = p0; ov.y = p1;
                *(uint2*)(msg + (size_t)slot * 128 + wc * 64 + lr * 4) = ov;
            }
        }
}

// ---- self-loop GEMM: out[n][o] = x[n]@loop_w[:,o] + bias[o]  (f32, no relu yet) ----
__global__ void k_selfgemm(const float* x, const float* loop_w, const float* bias,
                           float* out)
{
    __shared__ float4 WfS[2048];     // [i=64][o/4=32]
    __shared__ float4 xsS[1024];     // [n=64][i/4=16]
    int t = threadIdx.x, bid = blockIdx.x;
    int n0 = bid * 64;
    const float* xsf = (const float*)xsS;
    int q  = t & 31;
    int eb = t >> 5;
    float4 acc[8];
    for (int k = 0; k < 8; k++) { acc[k].x = 0.f; acc[k].y = 0.f; acc[k].z = 0.f; acc[k].w = 0.f; }
    for (int h = 0; h < 2; h++) {
        __syncthreads();
        const float4* Wsrc = (const float4*)(loop_w + h * 8192);
        for (int p = 0; p < 8; p++) WfS[p * 256 + t] = Wsrc[p * 256 + t];
        for (int p = 0; p < 4; p++) {
            int idx = p * 256 + t;
            int e = idx >> 4, c = idx & 15;
            int n = n0 + e; if (n >= N_NODES) n = N_NODES - 1;
            xsS[idx] = ((const float4*)(x + n * 128 + h * 64))[c];
        }
        __syncthreads();
        for (int i = 0; i < 64; i++) {
            float4 wv = WfS[i * 32 + q];
            for (int k = 0; k < 8; k++) {
                float xv = xsf[(eb + 8 * k) * 64 + i];
                acc[k].x += xv * wv.x;
                acc[k].y += xv * wv.y;
                acc[k].z += xv * wv.z;
                acc[k].w += xv * wv.w;
            }
        }
    }
    float4 b4 = *((const float4*)(bias + q * 4));
    for (int k = 0; k < 8; k++) {
        int n = n0 + eb + 8 * k;
        if (n < N_NODES) {
            float4 v;
            v.x = acc[k].x + b4.x;
            v.y = acc[k].y + b4.y;
            v.z = acc[k].z + b4.z;
            v.w = acc[k].w + b4.w;
            *((float4*)(out + (size_t)n * 128 + q * 4)) = v;
        }
    }
}

// ---- msg reduction: permuted-layout decode, 8 rows parallel, LDS tree,
//      final un-permute via 512B LDS exchange, coalesced out ----
__global__ void k_msgsum(const unsigned short* msg, const int* off2, float* out)
{
    __shared__ float4 red[256];
    __shared__ float fin[128];
    int n = blockIdx.x, t = threadIdx.x;
    int m0 = off2[n], m1 = off2[n + 1];
    int rp = t >> 5, c = t & 31;
    float4 a; a.x = 0.f; a.y = 0.f; a.z = 0.f; a.w = 0.f;
    for (int j = m0 + rp; j < m1; j += 8) {
        uint2 v = *(const uint2*)(msg + (size_t)j * 128 + c * 4);
        a.x += h2f((unsigned short)(v.x & 0xffff));   // n=0
        a.y += h2f((unsigned short)(v.x >> 16));      // n=1
        a.z += h2f((unsigned short)(v.y & 0xffff));   // n=2
        a.w += h2f((unsigned short)(v.y >> 16));      // n=3
    }
    red[t] = a;
    __syncthreads();
    if (t < 128) {
        float4 b = red[t + 128];
        red[t].x += b.x; red[t].y += b.y; red[t].z += b.z; red[t].w += b.w;
    }
    __syncthreads();
    if (t < 64) {
        float4 b = red[t + 64];
        red[t].x += b.x; red[t].y += b.y; red[t].z += b.z; red[t].w += b.w;
    }
    __syncthreads();
    if (t < 32) {
        float4 v = red[t], b = red[t + 32];
        v.x += b.x; v.y += b.y; v.z += b.z; v.w += b.w;
        // natural col for (c=t, n) = (t>>4)*64 + n*16 + (t&15)
        int base = (t >> 4) * 64 + (t & 15);
        fin[base]      = v.x;
        fin[base + 16] = v.y;
        fin[base + 32] = v.z;
        fin[base + 48] = v.w;
    }
    __syncthreads();
    if (t < 32) {
        float4 f = ((const float4*)fin)[t];
        float4 o = *(const float4*)(out + (size_t)n * 128 + t * 4);
        f.x += o.x; f.y += o.y; f.z += o.z; f.w += o.w;
        if (f.x < 0.f) f.x = 0.f;
        if (f.y < 0.f) f.y = 0.f;
        if (f.z < 0.f) f.z = 0.f;
        if (f.w < 0.f) f.w = 0.f;
        *(float4*)(out + (size_t)n * 128 + t * 4) = f;
    }
}

// ======================= fallback path (small ws) =======================

__global__ void k_wrel(const float* weight, const float* w_comp, float* W_rel)
{
    int idx = blockIdx.x * 256 + threadIdx.x;
    int r  = idx >> 14;
    int io = idx & 16383;
    float acc = 0.0f;
    for (int b = 0; b < B_BASES; b++)
        acc += w_comp[r * B_BASES + b] * weight[b * 16384 + io];
    W_rel[idx] = acc;
}

__global__ void k_zero(float* agg, int* counts, int* counts2)
{
    int idx = blockIdx.x * 256 + threadIdx.x;
    if (idx < N_NODES * 128) agg[idx] = 0.0f;
    if (idx < R_REL) counts[idx] = 0;
    if (idx < N_NODES) counts2[idx] = 0;
}

__global__ void k_hist(const int* etypes, int* counts)
{
    __shared__ int h[R_REL];
    int t = threadIdx.x;
    if (t < R_REL) h[t] = 0;
    __syncthreads();
    int e = blockIdx.x * 256 + t;
    atomicAdd(&h[etypes[e]], 1);
    __syncthreads();
    if (t < R_REL && h[t] != 0) atomicAdd(&counts[t], h[t]);
}

__global__ void k_scan(const int* counts, int* offsets, int* cursor, int* co)
{
    if (threadIdx.x == 0) {
        int run = 0, c = 0;
        for (int r = 0; r < R_REL; r++) {
            offsets[r] = run; cursor[r] = run; co[r] = c;
            run += counts[r];
            c   += (counts[r] + 63) >> 6;
        }
        offsets[R_REL] = run; co[R_REL] = c;
    }
}

__global__ void k_scatter(const int* etypes, int* cursor, int* perm)
{
    __shared__ int h[R_REL];
    __shared__ int base[R_REL];
    int t = threadIdx.x;
    if (t < R_REL) h[t] = 0;
    __syncthreads();
    int e = blockIdx.x * 256 + t;
    int et = etypes[e];
    int rank = atomicAdd(&h[et], 1);
    __syncthreads();
    if (t < R_REL && h[t] != 0) base[t] = atomicAdd(&cursor[t], h[t]);
    __syncthreads();
    perm[base[et] + rank] = e;
}

__global__ void k_edge_atomic(const float* x, const float* W_rel, const float* norm,
                              const int* src, const int* dst, const int* perm,
                              const int* offsets, const int* co, float* agg)
{
    __shared__ float4 WfS[2048];
    __shared__ float4 xsS[1024];
    __shared__ int coS[R_REL + 1];
    __shared__ int srcS[64], dstS[64];
    __shared__ float normS[64];
    int t = threadIdx.x, bid = blockIdx.x;
    if (t <= R_REL) coS[t] = co[t];
    __syncthreads();
    if (bid >= coS[R_REL]) return;
    int r = 0;
    while (bid >= coS[r + 1]) r++;
    int e0 = offsets[r] + (bid - coS[r]) * 64;
    int cnt = offsets[r + 1] - e0;
    if (cnt > 64) cnt = 64;
    if (t < 64) {
        if (t < cnt) {
            int eid = perm[e0 + t];
            srcS[t] = src[eid]; dstS[t] = dst[eid]; normS[t] = norm[eid];
        } else { srcS[t] = 0; dstS[t] = 0; normS[t] = 0.0f; }
    }
    const float* xsf = (const float*)xsS;
    int q  = t & 31;
    int eb = t >> 5;
    float4 acc[8];
    for (int k = 0; k < 8; k++) { acc[k].x = 0.f; acc[k].y = 0.f; acc[k].z = 0.f; acc[k].w = 0.f; }
    for (int h = 0; h < 2; h++) {
        __syncthreads();
        const float4* Wsrc = (const float4*)(W_rel + r * 16384 + h * 8192);
        for (int p = 0; p < 8; p++) WfS[p * 256 + t] = Wsrc[p * 256 + t];
        for (int p = 0; p < 4; p++) {
            int idx = p * 256 + t;
            int e = idx >> 4, c = idx & 15;
            xsS[idx] = ((const float4*)(x + srcS[e] * 128 + h * 64))[c];
        }
        __syncthreads();
        for (int i = 0; i < 64; i++) {
            float4 wv = WfS[i * 32 + q];
            for (int k = 0; k < 8; k++) {
                float xv = xsf[(eb + 8 * k) * 64 + i];
                acc[k].x += xv * wv.x;
                acc[k].y += xv * wv.y;
                acc[k].z += xv * wv.z;
                acc[k].w += xv * wv.w;
            }
        }
    }
    for (int k = 0; k < 8; k++) {
        int e = eb + 8 * k;
        if (e < cnt) {
            float nrm = normS[e];
            float* row = agg + dstS[e] * 128 + q * 4;
            atomicAdd(row + 0, acc[k].x * nrm);
            atomicAdd(row + 1, acc[k].y * nrm);
            atomicAdd(row + 2, acc[k].z * nrm);
            atomicAdd(row + 3, acc[k].w * nrm);
        }
    }
}

__global__ void k_out(const float* x, const float* loop_w, const float* agg,
                      const float* bias, float* out)
{
    __shared__ float xrow[128];
    int n = blockIdx.x;
    int o = threadIdx.x;
    xrow[o] = x[n * 128 + o];
    __syncthreads();
    float acc = 0.0f;
    for (int i = 0; i < 128; i++)
        acc += xrow[i] * loop_w[i * 128 + o];
    float val = acc + agg[n * 128 + o] + bias[o];
    if (val < 0.0f) val = 0.0f;
    out[n * 128 + o] = val;
}

extern "C" void kernel_launch(void* const* d_in, const int* in_sizes, int n_in,
                              void* d_out, int out_size, void* d_ws, size_t ws_size,
                              hipStream_t stream)
{
    const float* x      = (const float*)d_in[0];
    const float* weight = (const float*)d_in[1];
    const float* w_comp = (const float*)d_in[2];
    const float* h_bias = (const float*)d_in[3];
    const float* loop_w = (const float*)d_in[4];
    const float* norm   = (const float*)d_in[5];
    const int* src    = (const int*)d_in[6];
    const int* dst    = (const int*)d_in[7];
    const int* etypes = (const int*)d_in[8];
    float* out = (float*)d_out;

    char* ws = (char*)d_ws;
    size_t off = 0;
    float* W_rel = (float*)(ws + off); off += (size_t)R_REL * 16384 * 4;      // big: wt_h (2MB) + chunk_info in 4MB
    float* agg   = (float*)(ws + off); off += (size_t)N_NODES * 128 * 4;      // big: xh (5MB) + pnorm (2.5MB) in 10MB
    int* perm    = (int*)(ws + off);   off += (size_t)E_EDGES * 4;            // big: perm_src
    int* counts  = (int*)(ws + off);   off += 64 * 4;
    int* offsets = (int*)(ws + off);   off += 68 * 4;
    int* cursor  = (int*)(ws + off);   off += 64 * 4;
    int* co      = (int*)(ws + off);   off += 68 * 4;
    int* counts2 = (int*)(ws + off);   off += (size_t)N_NODES * 4;
    int* off2    = (int*)(ws + off);   off += (size_t)(N_NODES + 4) * 4;      // padded to keep 16B align
    int* cursor2 = (int*)(ws + off);   off += (size_t)N_NODES * 4;
    int* pos2    = (int*)(ws + off);   off += (size_t)E_EDGES * 4;
    unsigned short* msg = (unsigned short*)(ws + off);
    size_t need_big = off + (size_t)E_EDGES * 128 * 2;
    int big = (ws_size >= need_big) ? 1 : 0;

    if (big) {
        // overlays (big path only)
        unsigned short* wt_h = (unsigned short*)W_rel;                         // 2MB
        char* wspare = (char*)W_rel + (size_t)2 * 1024 * 1024;
        int2* chunk_info = (int2*)wspare;                                      // <=96KB
        unsigned short* xh = (unsigned short*)agg;                             // 5MB
        float* pnorm = (float*)((char*)agg + (size_t)N_NODES * 128 * 2);       // 2.5MB
        int* perm_src = perm;
        // scratch inside msg region (consumed before k_edge_mfma writes msg)
        int* hp = (int*)msg;                                                   // NSEG*N_NODES*4 = 10.24MB
        int* he = (int*)((char*)msg + (size_t)NSEG * N_NODES * 4);             // 2*NSEG*64*4 = 64KB
        int* be = (int*)((char*)he + (size_t)2 * NSEG * 64 * 4);               // 64KB

        k_wrelh<<<R_REL * 16, 256, 0, stream>>>(weight, w_comp, wt_h);
        k_xhalf<<<(N_NODES * 128 / 4) / 256, 256, 0, stream>>>(x, xh);
        k_histp<<<2 * NSEG, 256, 0, stream>>>(etypes, dst, hp, he);
        k_sumc<<<(N_NODES + 255) / 256, 256, 0, stream>>>(hp, counts2);
        k_scan_all2<<<1, 1024, 0, stream>>>(he, counts2, offsets, co, off2, be, chunk_info);
        k_segbase<<<(N_NODES + 255) / 256, 256, 0, stream>>>(off2, hp);
        k_scatter3<<<2 * NSEG, 256, 0, stream>>>(etypes, dst, src, norm,
                                                 hp, be, perm_src, pnorm, pos2);
        k_edge_mfma<<<E_EDGES / 64 + R_REL, 256, 0, stream>>>(
            xh, wt_h, perm_src, pnorm, pos2, chunk_info, co, msg);
        k_selfgemm<<<(N_NODES + 63) / 64, 256, 0, stream>>>(x, loop_w, h_bias, out);
        k_msgsum<<<N_NODES, 256, 0, stream>>>(msg, off2, out);
    } else {
        k_wrel<<<(R_REL * 16384) / 256, 256, 0, stream>>>(weight, w_comp, W_rel);
        k_zero<<<(N_NODES * 128) / 256, 256, 0, stream>>>(agg, counts, counts2);
        k_hist<<<E_EDGES / 256, 256, 0, stream>>>(etypes, counts);
        k_scan<<<1, 64, 0, stream>>>(counts, offsets, cursor, co);
        k_scatter<<<E_EDGES / 256, 256, 0, stream>>>(etypes, cursor, perm);
        k_edge_atomic<<<E_EDGES / 64 + R_REL, 256, 0, stream>>>(
            x, W_rel, norm, src, dst, perm, offsets, co, agg);
        k_out<<<N_NODES, 128, 0, stream>>>(x, loop_w, agg, h_bias, out);
    }
}